// Round 10
// baseline (1406.811 us; speedup 1.0000x reference)
//
#include <hip/hip_runtime.h>
#include <hip/hip_fp8.h>

typedef float f32x4 __attribute__((ext_vector_type(4)));
typedef float f32x16 __attribute__((ext_vector_type(16)));
typedef short s16x8 __attribute__((ext_vector_type(8)));
typedef short s16x4 __attribute__((ext_vector_type(4)));
typedef unsigned short ush;
typedef unsigned char u8;

constexpr int Bn = 4, Tn = 1024, Dn = 512, CAPn = 32768, Kn = 1024;
constexpr int ROWS = Bn * Tn; // 4096
constexpr float SCALE = 0.044194173824159216f; // 1/sqrt(512)
constexpr float SC64 = SCALE / 64.0f;          // nm8 stored as 64*M
constexpr float MOM = 0.99f;
constexpr float RATE_B = 0.0025f; // 0.01 / B

// ---- workspace layout (byte offsets). ws proven >= 102.0e6 B ----
constexpr size_t OFF_NM8   = 0;                      // fp8 [CAP][D] (late) 16.78M
constexpr size_t OFF_Q8    = 16777216;               // fp8 [ROWS][D] (mid) 2.10M
constexpr size_t OFF_NMT   = 33554432;               // bf16 [D][CAP] (alias: mem f16 early)
constexpr size_t OFF_OPART = 67108864;               // bf16 [8][ROWS][D] (late) -- UNION with:
constexpr size_t OFF_KHF   = 67108864;               //   f16 [ROWS][D] (early)
constexpr size_t OFF_ZPART = 75497472;               //   f32 [512][ROWS] (early)
constexpr size_t OFF_PRIO  = 83886080;               //   f32 [4][CAP] (early)
constexpr size_t OFF_RANK  = 84410368;               //   i32 [4][CAP] (early)
constexpr size_t OFF_COMB  = 84934656;               //   f32 [4] (early; +64: invl1)
constexpr size_t OFF_ZP2   = 100663296;              // f32 [8][ROWS] (late)

#define MFMAH(a, b, c) __builtin_amdgcn_mfma_f32_16x16x32_f16((a), (b), (c), 0, 0, 0)
#define MFMA8(a, b, c) __builtin_amdgcn_mfma_f32_32x32x16_fp8_fp8((a), (b), (c), 0, 0, 0)
#define MFMAB(a, b, c) __builtin_amdgcn_mfma_f32_32x32x16_bf16((a), (b), (c), 0, 0, 0)

__device__ __forceinline__ ush bfrn(float x) {
  unsigned u = __float_as_uint(x);
  return (ush)((u + 0x7FFFu + ((u >> 16) & 1u)) >> 16);
}
__device__ __forceinline__ float bff(ush h) { return __uint_as_float(((unsigned)h) << 16); }
__device__ __forceinline__ ush f16rn(float x) {
  _Float16 h = (_Float16)x;
  return *(ush*)&h;
}
__device__ __forceinline__ u8 f8rn(float x) {
  __hip_fp8_e4m3 v(x);
  return (u8)v.__x;
}

__device__ __forceinline__ void gl16(const void* g, void* l) {
  __builtin_amdgcn_global_load_lds(
      (const __attribute__((address_space(1))) void*)(uintptr_t)g,
      (__attribute__((address_space(3))) void*)(uintptr_t)l, 16, 0, 0);
}

// combined[b] = mean(importance[b,:,0])
__global__ void k_combined(const float* __restrict__ imp, float* __restrict__ comb) {
  __shared__ float red[256];
  int b = blockIdx.x;
  float s = 0.f;
  for (int t = threadIdx.x; t < Tn; t += 256) s += imp[(size_t)b * Tn + t];
  red[threadIdx.x] = s;
  __syncthreads();
  for (int off = 128; off > 0; off >>= 1) {
    if (threadIdx.x < (unsigned)off) red[threadIdx.x] += red[threadIdx.x + off];
    __syncthreads();
  }
  if (threadIdx.x == 0) comb[b] = red[0] * (1.0f / Tn);
}

// x -> f16 (RTN). 4 elems/thread.
__global__ void k_cvt_f16(const float* __restrict__ x, ush* __restrict__ o) {
  size_t i = ((size_t)blockIdx.x * 256 + threadIdx.x) * 4;
  f32x4 v = *(const f32x4*)&x[i];
  s16x4 h;
#pragma unroll
  for (int j = 0; j < 4; ++j) h[j] = (short)f16rn(v[j]);
  *(s16x4*)&o[i] = h;
}

// x -> fp8 e4m3 (scale 1). 4 elems/thread.
__global__ void k_cvt_fp8(const float* __restrict__ x, u8* __restrict__ o) {
  size_t i = ((size_t)blockIdx.x * 256 + threadIdx.x) * 4;
  f32x4 v = *(const f32x4*)&x[i];
  union { u8 b[4]; unsigned w; } r;
#pragma unroll
  for (int j = 0; j < 4; ++j) r.b[j] = f8rn(v[j]);
  *(unsigned*)&o[i] = r.w;
}

// Z partials: zpart[cb][t] = sum over this block's 64 c of exp(A[c,:].B[t,:])
__global__ __launch_bounds__(256, 2) void k_rowexp(const ush* __restrict__ Ahf,
                                                   const ush* __restrict__ Bhf,
                                                   float* __restrict__ zpart) {
  __shared__ ush Bs[64 * 512];
  __shared__ float red[2][64];
  const int tid = threadIdx.x;
  const int lane = tid & 63, wid = tid >> 6;
  const int wc2 = wid >> 1, wt = wid & 1;
  const int l15 = lane & 15, g = lane >> 4;
  const int cb = blockIdx.x;
  const int cBase = cb * 64;

  s16x8 afr[2][16];
#pragma unroll
  for (int mi = 0; mi < 2; ++mi) {
    int c = cBase + wc2 * 32 + mi * 16 + l15;
#pragma unroll
    for (int ks = 0; ks < 16; ++ks)
      afr[mi][ks] = *(const s16x8*)&Ahf[(size_t)c * Dn + ks * 32 + g * 8];
  }

  for (int tt = 0; tt < 64; ++tt) {
    const int tBase = tt * 64;
#pragma unroll
    for (int rr = 0; rr < 16; ++rr) {
      int idx = rr * 256 + tid;
      int row = idx >> 6, ch = idx & 63;
      gl16(&Bhf[(size_t)(tBase + row) * Dn + ((ch ^ (row & 7)) << 3)],
           &Bs[rr * 2048 + wid * 512]);
    }
    __syncthreads();
    f32x4 S[2][2];
#pragma unroll
    for (int mi = 0; mi < 2; ++mi)
#pragma unroll
      for (int ni = 0; ni < 2; ++ni) S[mi][ni] = (f32x4){0.f, 0.f, 0.f, 0.f};
#pragma unroll
    for (int ks = 0; ks < 16; ++ks) {
      s16x8 bfr[2];
#pragma unroll
      for (int ni = 0; ni < 2; ++ni) {
        int trow = wt * 32 + ni * 16 + l15;
        bfr[ni] = *(const s16x8*)&Bs[trow * 512 + (((ks * 4 + g) ^ (trow & 7)) * 8)];
      }
#pragma unroll
      for (int mi = 0; mi < 2; ++mi)
#pragma unroll
        for (int ni = 0; ni < 2; ++ni) S[mi][ni] = MFMAH(afr[mi][ks], bfr[ni], S[mi][ni]);
    }
    float tacc[2] = {0.f, 0.f};
#pragma unroll
    for (int mi = 0; mi < 2; ++mi)
#pragma unroll
      for (int ni = 0; ni < 2; ++ni)
#pragma unroll
        for (int r = 0; r < 4; ++r) tacc[ni] += __expf(S[mi][ni][r]);
#pragma unroll
    for (int ni = 0; ni < 2; ++ni) {
      float v = tacc[ni];
      v += __shfl_xor(v, 16);
      v += __shfl_xor(v, 32);
      tacc[ni] = v;
    }
    if (g == 0) {
      red[wc2][wt * 32 + l15] = tacc[0];
      red[wc2][wt * 32 + 16 + l15] = tacc[1];
    }
    __syncthreads();
    if (tid < 64) zpart[(size_t)cb * ROWS + tBase + tid] = red[0][tid] + red[1][tid];
  }
}

__global__ void k_invl(const float* __restrict__ zpart, float* __restrict__ invl) {
  int t = blockIdx.x * 256 + threadIdx.x;
  float s = 0.f;
  for (int cb = 0; cb < 512; ++cb) s += zpart[(size_t)cb * ROWS + t];
  invl[t] = 1.0f / s;
}

// prio[b,c] = comb[b] + 0.1 * sum_t exp(scores[b,t,c]) * invl1[b,t]  (f16 MFMA)
__global__ __launch_bounds__(256, 2) void k_usage(const ush* __restrict__ mhf,
                                                  const ush* __restrict__ khf,
                                                  const float* __restrict__ invl,
                                                  const float* __restrict__ comb,
                                                  float* __restrict__ prio) {
  __shared__ ush Ah[128 * 64], Bh[128 * 64];
  const int tid = threadIdx.x;
  const int lane = tid & 63, w = tid >> 6;
  const int l15 = lane & 15, g = lane >> 4;
  const int cBase = blockIdx.x * 128;
  const int b = blockIdx.y;
  const ush* khb = khf + (size_t)b * Tn * Dn;
  const int r0 = tid >> 3, u0 = tid & 7;
  const int usw = (u0 ^ (r0 & 7)) << 3;

  float uacc[2][4] = {{0.f, 0.f, 0.f, 0.f}, {0.f, 0.f, 0.f, 0.f}};
  for (int tt = 0; tt < 8; ++tt) {
    f32x4 S[2][8];
#pragma unroll
    for (int mi = 0; mi < 2; ++mi)
#pragma unroll
      for (int ni = 0; ni < 8; ++ni) S[mi][ni] = (f32x4){0.f, 0.f, 0.f, 0.f};
    for (int kk = 0; kk < 8; ++kk) {
      __syncthreads();
      {
        size_t a0 = (size_t)(cBase + r0) * Dn + kk * 64 + usw;
        size_t a1 = (size_t)(cBase + r0 + 64) * Dn + kk * 64 + usw;
        gl16(&mhf[a0], &Ah[w * 512]);
        gl16(&mhf[a1], &Ah[4096 + w * 512]);
        size_t b0 = (size_t)(tt * 128 + r0) * Dn + kk * 64 + usw;
        size_t b1 = (size_t)(tt * 128 + r0 + 64) * Dn + kk * 64 + usw;
        gl16(&khb[b0], &Bh[w * 512]);
        gl16(&khb[b1], &Bh[4096 + w * 512]);
      }
      __syncthreads();
#pragma unroll
      for (int ks2 = 0; ks2 < 2; ++ks2) {
        s16x8 ah[2];
#pragma unroll
        for (int mi = 0; mi < 2; ++mi) {
          int crow = w * 32 + mi * 16 + l15;
          ah[mi] = *(const s16x8*)&Ah[crow * 64 + (((ks2 * 4 + g) ^ (crow & 7)) * 8)];
        }
#pragma unroll
        for (int ni = 0; ni < 8; ++ni) {
          int trow = ni * 16 + l15;
          s16x8 bh = *(const s16x8*)&Bh[trow * 64 + (((ks2 * 4 + g) ^ (trow & 7)) * 8)];
#pragma unroll
          for (int mi = 0; mi < 2; ++mi) S[mi][ni] = MFMAH(ah[mi], bh, S[mi][ni]);
        }
      }
    }
#pragma unroll
    for (int ni = 0; ni < 8; ++ni) {
      float il = invl[b * Tn + tt * 128 + ni * 16 + l15];
#pragma unroll
      for (int mi = 0; mi < 2; ++mi)
#pragma unroll
        for (int r = 0; r < 4; ++r) uacc[mi][r] += __expf(S[mi][ni][r]) * il;
    }
  }
#pragma unroll
  for (int mi = 0; mi < 2; ++mi)
#pragma unroll
    for (int r = 0; r < 4; ++r) {
      float v = uacc[mi][r];
      v += __shfl_xor(v, 1);
      v += __shfl_xor(v, 2);
      v += __shfl_xor(v, 4);
      v += __shfl_xor(v, 8);
      if (l15 == 0)
        prio[(size_t)b * CAPn + cBase + w * 32 + mi * 16 + g * 4 + r] =
            comb[b] + 0.1f * v;
    }
}

// rank init: unselected slots get Kn
__global__ void k_rankinit(int* __restrict__ rank) {
  rank[blockIdx.x * 256 + threadIdx.x] = Kn;
}

// Per-batch exact top-K selection + stable rank (jax top_k semantics).
__global__ __launch_bounds__(1024) void k_select(const float* __restrict__ prio,
                                                 int* __restrict__ rank) {
  const int b = blockIdx.x;
  const float* p = prio + (size_t)b * CAPn;
  __shared__ int hist[256];
  __shared__ unsigned long long s_pref;
  __shared__ int s_krem;
  __shared__ int s_cnt;
  __shared__ unsigned long long selk[Kn];
  const int tid = threadIdx.x;
  if (tid == 0) { s_pref = 0ull; s_krem = Kn; s_cnt = 0; }

#define KEYOF(c, kk)                                                         \
  {                                                                          \
    unsigned mb_ = __float_as_uint(p[(c)]);                                  \
    mb_ = (mb_ & 0x80000000u) ? ~mb_ : (mb_ | 0x80000000u);                  \
    (kk) = ((unsigned long long)mb_ << 32) | (unsigned)(0xFFFFFFFFu - (c));  \
  }

  __syncthreads();
  for (int pos = 56; pos >= 0; pos -= 8) {
    if (tid < 256) hist[tid] = 0;
    __syncthreads();
    unsigned long long pref = s_pref;
    unsigned long long maskhi = (pos == 56) ? 0ull : (~0ull << (pos + 8));
    for (int c = tid; c < CAPn; c += 1024) {
      unsigned long long k;
      KEYOF(c, k);
      if ((k & maskhi) == pref) atomicAdd(&hist[(int)((k >> pos) & 255)], 1);
    }
    __syncthreads();
    if (tid == 0) {
      int krem = s_krem;
      int d = 255;
      for (;; --d) {
        int h = hist[d];
        if (krem <= h || d == 0) break;
        krem -= h;
      }
      s_pref = pref | ((unsigned long long)d << pos);
      s_krem = krem;
    }
    __syncthreads();
  }
  unsigned long long T = s_pref;
  for (int c = tid; c < CAPn; c += 1024) {
    unsigned long long k;
    KEYOF(c, k);
    if (k >= T) {
      int idx = atomicAdd(&s_cnt, 1);
      selk[idx] = k;
    }
  }
  __syncthreads();
  unsigned long long mine = selk[tid];
  int r = 0;
  for (int j = 0; j < Kn; ++j) r += (selk[j] > mine) ? 1 : 0;
  int c = (int)(0xFFFFFFFFu - (unsigned)(mine & 0xFFFFFFFFull));
  rank[(size_t)b * CAPn + c] = r;
#undef KEYOF
}

// nm8 (fp8 e4m3) = 64 * (0.99*mem + 0.0025*sum_b selected values)
__global__ void k_newmem8(const float* __restrict__ mem, const float* __restrict__ values,
                          const int* __restrict__ rank, u8* __restrict__ nm8) {
  int gid = blockIdx.x * 256 + threadIdx.x;
  int c = gid >> 7;
  int q = (gid & 127) << 2;
  f32x4 m = *(const f32x4*)&mem[(size_t)c * Dn + q];
  f32x4 acc = {0.f, 0.f, 0.f, 0.f};
#pragma unroll
  for (int b = 0; b < Bn; ++b) {
    int r = rank[(size_t)b * CAPn + c];
    if (r < Kn) acc += *(const f32x4*)&values[((size_t)b * Tn + r) * Dn + q];
  }
  f32x4 res = (m * MOM + acc * RATE_B) * 64.0f;
  union { u8 b[4]; unsigned w; } out;
#pragma unroll
  for (int j = 0; j < 4; ++j) out.b[j] = f8rn(res[j]);
  *(unsigned*)&nm8[(size_t)c * Dn + q] = out.w;
}

// nmT[d][c] = new_mem[c][d] (bf16), recomputed from mem/values/rank per tile.
__global__ __launch_bounds__(256) void k_nmT(const float* __restrict__ mem,
                                             const float* __restrict__ values,
                                             const int* __restrict__ rank,
                                             ush* __restrict__ nmT) {
  __shared__ ush tile[64][65];
  int cBase = blockIdx.x * 64, dBase = blockIdx.y * 64;
  int tid = threadIdx.x;
  int c = tid >> 2, dq = (tid & 3) * 16;
  int rr[4];
#pragma unroll
  for (int b = 0; b < Bn; ++b) rr[b] = rank[(size_t)b * CAPn + cBase + c];
#pragma unroll
  for (int j = 0; j < 4; ++j) {
    f32x4 m = *(const f32x4*)&mem[(size_t)(cBase + c) * Dn + dBase + dq + j * 4];
    f32x4 a = {0.f, 0.f, 0.f, 0.f};
#pragma unroll
    for (int b = 0; b < Bn; ++b)
      if (rr[b] < Kn)
        a += *(const f32x4*)&values[((size_t)b * Tn + rr[b]) * Dn + dBase + dq + j * 4];
    f32x4 res = m * MOM + a * RATE_B;
#pragma unroll
    for (int jj = 0; jj < 4; ++jj) tile[c][dq + j * 4 + jj] = bfrn(res[jj]);
  }
  __syncthreads();
  int drow = tid >> 2, cq = (tid & 3) * 16;
#pragma unroll
  for (int k = 0; k < 2; ++k) {
    s16x8 v;
#pragma unroll
    for (int j = 0; j < 8; ++j) v[j] = (short)tile[cq + k * 8 + j][drow];
    *(s16x8*)&nmT[(size_t)(dBase + drow) * CAPn + cBase + cq + k * 8] = v;
  }
}

// Fused attn, 32x32 MFMA: QK = fp8x fp8 (32x32x16, 8B frags), PV = bf16 (32x32x16).
// Grid (8 cy, 32 qt), 8 waves. QK: wave = (cw c-tile 32, qh q-half 64); Q8 frags
// from global (L2-hot). PV: wave = (dw 128d, qh). r5-style sync, dbuf, 13 phases/ct.
// LDS: MS8 fp8 [2][128c][128k] 32KB @0; MT bf16 [2][512d][16c] 32KB @32768;
//      PS bf16 [128q][128c] 32KB @65536 (epilogue reuses as [32q][512d]).
__global__ __launch_bounds__(512, 1) void k_attnout(
    const u8* __restrict__ q8, const u8* __restrict__ nm8,
    const ush* __restrict__ nmT, ush* __restrict__ opart,
    float* __restrict__ zp2) {
  __shared__ __align__(16) u8 L[98304];
  __shared__ float zredw[4][128];
  __shared__ float zacc[128];
  constexpr int LMS = 0, LMT = 32768, LPS = 65536;
  const int tid = threadIdx.x;
  const int lane = tid & 63, w = tid >> 6;
  const int l31 = lane & 31, h = lane >> 5;
  const int cw = w & 3, qh = w >> 2;  // cw doubles as dw in PV
  const int cy = blockIdx.x;
  const int qBase = blockIdx.y * 128;

  auto stage_ms8 = [&](int buf, int cb_, int kk) {
#pragma unroll
    for (int j = 0; j < 2; ++j) {
      int u = (w * 2 + j) * 64 + lane;
      int c = u >> 3, s = u & 7;
      gl16(&nm8[(size_t)(cb_ + c) * Dn + kk * 128 + ((s ^ (c & 7)) * 16)],
           &L[LMS + buf * 16384 + (w * 2 + j) * 1024]);
    }
  };
  auto stage_mt = [&](int buf, int cb_, int pc) {
#pragma unroll
    for (int j = 0; j < 2; ++j) {
      int u = (w * 2 + j) * 64 + lane;
      int d = u >> 1, s = u & 1;
      gl16(&nmT[(size_t)d * CAPn + cb_ + pc * 16 + ((s ^ (d & 1)) * 8)],
           &L[LMT + buf * 16384 + (w * 2 + j) * 1024]);
    }
  };

  // Q8 row pointers (col q = l31 within each 32-q tile; k-sub h*8)
  const u8* qp[2];
  qp[0] = q8 + (size_t)(qBase + qh * 64 + l31) * Dn + h * 8;
  qp[1] = qp[0] + (size_t)32 * Dn;

  f32x16 O[8];  // PV acc: tiles (t d-idx 0..3) x (tq 0..1); idx = t*2+tq
#pragma unroll
  for (int i = 0; i < 8; ++i) O[i] = (f32x16)(0.f);
  if (tid < 128) zacc[tid] = 0.f;

  const int s7 = l31 & 7;
  const u8* amp = &L[LMS + (cw * 32 + l31) * 128 + h * 8];

  stage_ms8(0, cy * 4096, 0);
  __syncthreads();

  for (int ct = 0; ct < 32; ++ct) {
    const int cBase = cy * 4096 + ct * 128;
    const int cNext = cy * 4096 + ((ct + 1) & 31) * 128;

    // ---- QK phases kk=0..3 (K-chunks of 128), fp8 32x32x16 ----
    f32x16 S[2];
    S[0] = (f32x16)(0.f);
    S[1] = (f32x16)(0.f);
#pragma unroll
    for (int kk = 0; kk < 4; ++kk) {
      if (kk < 3) stage_ms8((kk + 1) & 1, cBase, kk + 1);
      else stage_mt(0, cBase, 0);
      const u8* ab = amp + (kk & 1) * 16384;
      const u8* qb0 = qp[0] + kk * 128;
      const u8* qb1 = qp[1] + kk * 128;
#pragma unroll
      for (int ks = 0; ks < 8; ++ks) {
        long a = *(const long*)&ab[(ks ^ s7) * 16];
        long b0 = *(const long*)&qb0[ks * 16];
        long b1 = *(const long*)&qb1[ks * 16];
        S[0] = MFMA8(a, b0, S[0]);
        S[1] = MFMA8(a, b1, S[1]);
      }
      __syncthreads();
    }

    // ---- P phase: exp(S*SC64) -> PS [128q][128c]; z partials ----
#pragma unroll
    for (int t = 0; t < 2; ++t) {
      int q = qh * 64 + t * 32 + l31;
      float zl = 0.f;
#pragma unroll
      for (int r2 = 0; r2 < 4; ++r2) {
        s16x4 p;
#pragma unroll
        for (int j = 0; j < 4; ++j) {
          float e = __expf(S[t][r2 * 4 + j] * SC64);
          zl += e;
          p[j] = (short)bfrn(e);
        }
        int u8i = cw * 8 + r2 * 2 + h;
        int u8s = u8i ^ ((q & 15) << 1);
        *(s16x4*)&L[LPS + q * 256 + u8s * 8] = p;
      }
      zl += __shfl_xor(zl, 32);
      if (h == 0) zredw[cw][q] = zl;
    }
    __syncthreads();

    // ---- PV phases pc=0..7 (16c each), bf16 32x32x16 ----
#pragma unroll
    for (int pc = 0; pc < 8; ++pc) {
      if (pc == 0) {
        if (tid < 128)
          zacc[tid] += (zredw[0][tid] + zredw[1][tid]) + (zredw[2][tid] + zredw[3][tid]);
      }
      if (pc < 7) stage_mt((pc + 1) & 1, cBase, pc + 1);
      else stage_ms8(0, cNext, 0);
      s16x8 pb[2];
#pragma unroll
      for (int tq = 0; tq < 2; ++tq) {
        int q = qh * 64 + tq * 32 + l31;
        int u16 = (pc * 2 + h) ^ (q & 15);
        pb[tq] = *(const s16x8*)&L[LPS + q * 256 + u16 * 16];
      }
#pragma unroll
      for (int t = 0; t < 4; ++t) {
        int d = cw * 128 + t * 32 + l31;
        s16x8 am = *(const s16x8*)&L[LMT + (pc & 1) * 16384 + d * 32 + ((h ^ (d & 1)) * 16)];
        O[t * 2 + 0] = MFMAB(am, pb[0], O[t * 2 + 0]);
        O[t * 2 + 1] = MFMAB(am, pb[1], O[t * 2 + 1]);
      }
      __syncthreads();
    }
  }

  // ---- epilogue: z store + O via LDS transpose (4 q-window passes) ----
  if (tid < 128) zp2[(size_t)cy * ROWS + qBase + tid] = zacc[tid];
#pragma unroll
  for (int p = 0; p < 4; ++p) {
    __syncthreads();
    if (qh == (p >> 1)) {
      const int tq = p & 1;
#pragma unroll
      for (int t = 0; t < 4; ++t)
#pragma unroll
        for (int r2 = 0; r2 < 4; ++r2) {
          s16x4 ov;
#pragma unroll
          for (int j = 0; j < 4; ++j) ov[j] = (short)bfrn(O[t * 2 + tq][r2 * 4 + j]);
          int u8i = cw * 32 + t * 8 + r2 * 2 + h;  // d>>2
          int u8s = u8i ^ ((l31 & 15) << 1);
          *(s16x4*)&L[LPS + l31 * 1024 + u8s * 8] = ov;
        }
    }
    __syncthreads();
#pragma unroll
    for (int i = 0; i < 4; ++i) {
      int u16i = i * 512 + tid;
      int ql = u16i >> 6, u16 = u16i & 63;
      s16x8 v = *(const s16x8*)&L[LPS + ql * 1024 + ((u16 ^ (ql & 15)) * 16)];
      *(s16x8*)&opart[((size_t)cy * ROWS + qBase + p * 32 + ql) * Dn + u16 * 8] = v;
    }
  }
}

// out = (sum_cy opart[cy]) / (sum_cy zp2[cy]) per row
__global__ void k_merge(const ush* __restrict__ opart, const float* __restrict__ zp2,
                        float* __restrict__ out) {
  size_t i = ((size_t)blockIdx.x * 256 + threadIdx.x) * 4;
  int row = (int)(i >> 9);
  float z = 0.f;
#pragma unroll
  for (int cyy = 0; cyy < 8; ++cyy) z += zp2[(size_t)cyy * ROWS + row];
  float inv = 1.0f / z;
  f32x4 acc = {0.f, 0.f, 0.f, 0.f};
#pragma unroll
  for (int cyy = 0; cyy < 8; ++cyy) {
    s16x4 a = *(const s16x4*)&opart[(size_t)cyy * ROWS * Dn + i];
#pragma unroll
    for (int j = 0; j < 4; ++j) acc[j] += bff((ush)a[j]);
  }
#pragma unroll
  for (int j = 0; j < 4; ++j) acc[j] *= inv;
  *(f32x4*)&out[i] = acc;
}

extern "C" void kernel_launch(void* const* d_in, const int* in_sizes, int n_in,
                              void* d_out, int out_size, void* d_ws, size_t ws_size,
                              hipStream_t stream) {
  const float* keys = (const float*)d_in[0];
  const float* values = (const float*)d_in[1];
  const float* importance = (const float*)d_in[2];
  const float* query = (const float*)d_in[3];
  const float* mem = (const float*)d_in[4];
  char* wsb = (char*)d_ws;
  u8* nm8    = (u8*)(wsb + OFF_NM8);
  u8* q8     = (u8*)(wsb + OFF_Q8);
  ush* nmT   = (ush*)(wsb + OFF_NMT);
  ush* mhf   = (ush*)(wsb + OFF_NMT);  // alias (dead after k_usage; nmT written later)
  ush* khf   = (ush*)(wsb + OFF_KHF);
  ush* opart = (ush*)(wsb + OFF_OPART);
  float* zpart = (float*)(wsb + OFF_ZPART);
  float* prio  = (float*)(wsb + OFF_PRIO);
  int* rank    = (int*)(wsb + OFF_RANK);
  float* comb  = (float*)(wsb + OFF_COMB);
  float* zp2   = (float*)(wsb + OFF_ZP2);
  float* invl1 = (float*)(wsb + OFF_COMB + 64);
  float* out = (float*)d_out;

  k_combined<<<Bn, 256, 0, stream>>>(importance, comb);
  k_cvt_f16<<<(ROWS * Dn / 4) / 256, 256, 0, stream>>>(keys, khf);
  k_cvt_f16<<<(CAPn * Dn / 4) / 256, 256, 0, stream>>>(mem, mhf);
  k_cvt_fp8<<<(ROWS * Dn / 4) / 256, 256, 0, stream>>>(query, q8);
  k_rowexp<<<CAPn / 64, 256, 0, stream>>>(mhf, khf, zpart);
  k_invl<<<ROWS / 256, 256, 0, stream>>>(zpart, invl1);
  k_usage<<<dim3(CAPn / 128, Bn), 256, 0, stream>>>(mhf, khf, invl1, comb, prio);
  k_rankinit<<<(Bn * CAPn) / 256, 256, 0, stream>>>(rank);
  k_select<<<Bn, 1024, 0, stream>>>(prio, rank);
  k_newmem8<<<(CAPn * Dn / 4) / 256, 256, 0, stream>>>(mem, values, rank, nm8);
  k_nmT<<<dim3(CAPn / 64, Dn / 64), 256, 0, stream>>>(mem, values, rank, nmT);
  k_attnout<<<dim3(8, ROWS / 128), 512, 0, stream>>>(q8, nm8, nmT, opart, zp2);
  k_merge<<<(ROWS * Dn / 4) / 256, 256, 0, stream>>>(opart, zp2, out);
}

// Round 11
// 959.254 us; speedup vs baseline: 1.4666x; 1.4666x over previous
//
#include <hip/hip_runtime.h>

typedef float f32x4 __attribute__((ext_vector_type(4)));
typedef short s16x8 __attribute__((ext_vector_type(8)));
typedef short s16x4 __attribute__((ext_vector_type(4)));
typedef unsigned short ush;

constexpr int Bn = 4, Tn = 1024, Dn = 512, CAPn = 32768, Kn = 1024;
constexpr int ROWS = Bn * Tn; // 4096
constexpr float SCALE = 0.044194173824159216f; // 1/sqrt(512)
constexpr float MOM = 0.99f;
constexpr float RATE_B = 0.0025f; // 0.01 / B

// ---- workspace layout (byte offsets). Total 100.79e6 B (proven ws >= 102.0e6 B) ----
constexpr size_t OFF_NM    = 0;                      // bf16 [CAP][D] (late)
constexpr size_t OFF_NMT   = 33554432;               // bf16 [D][CAP] (alias: mem f16 early)
constexpr size_t OFF_OPART = 67108864;               // bf16 [8][ROWS][D] (late)  -- UNION with:
constexpr size_t OFF_KHF   = 67108864;               //   f16 [ROWS][D] (early)
constexpr size_t OFF_ZPART = 75497472;               //   f32 [512][ROWS] (early)
constexpr size_t OFF_PRIO  = 83886080;               //   f32 [4][CAP] (early)
constexpr size_t OFF_RANK  = 84410368;               //   i32 [4][CAP] (early)
constexpr size_t OFF_COMB  = 84934656;               //   f32 [4] (early; +64: invl1)
constexpr size_t OFF_ZP2   = 100663296;              // f32 [8][ROWS] (late)

#define MFMA(a, b, c) __builtin_amdgcn_mfma_f32_16x16x32_bf16((a), (b), (c), 0, 0, 0)
#define MFMAH(a, b, c) __builtin_amdgcn_mfma_f32_16x16x32_f16((a), (b), (c), 0, 0, 0)

__device__ __forceinline__ ush bfrn(float x) {
  unsigned u = __float_as_uint(x);
  return (ush)((u + 0x7FFFu + ((u >> 16) & 1u)) >> 16);
}
__device__ __forceinline__ float bff(ush h) { return __uint_as_float(((unsigned)h) << 16); }
__device__ __forceinline__ ush f16rn(float x) {
  _Float16 h = (_Float16)x;  // v_cvt_f16_f32, RTN
  return *(ush*)&h;
}

__device__ __forceinline__ void gl16(const ush* g, ush* l) {
  __builtin_amdgcn_global_load_lds(
      (const __attribute__((address_space(1))) void*)(uintptr_t)g,
      (__attribute__((address_space(3))) void*)(uintptr_t)l, 16, 0, 0);
}

// combined[b] = mean(importance[b,:,0])
__global__ void k_combined(const float* __restrict__ imp, float* __restrict__ comb) {
  __shared__ float red[256];
  int b = blockIdx.x;
  float s = 0.f;
  for (int t = threadIdx.x; t < Tn; t += 256) s += imp[(size_t)b * Tn + t];
  red[threadIdx.x] = s;
  __syncthreads();
  for (int off = 128; off > 0; off >>= 1) {
    if (threadIdx.x < (unsigned)off) red[threadIdx.x] += red[threadIdx.x + off];
    __syncthreads();
  }
  if (threadIdx.x == 0) comb[b] = red[0] * (1.0f / Tn);
}

// x -> f16 (RTN). 4 elems/thread.
__global__ void k_cvt_f16(const float* __restrict__ x, ush* __restrict__ o) {
  size_t i = ((size_t)blockIdx.x * 256 + threadIdx.x) * 4;
  f32x4 v = *(const f32x4*)&x[i];
  s16x4 h;
#pragma unroll
  for (int j = 0; j < 4; ++j) h[j] = (short)f16rn(v[j]);
  *(s16x4*)&o[i] = h;
}

// Z partials: zpart[cb][t] = sum over this block's 64 c of exp(A[c,:].B[t,:])
// f16 inputs, f16 MFMA. A rows in registers; B staged via gl16.
__global__ __launch_bounds__(256, 2) void k_rowexp(const ush* __restrict__ Ahf,
                                                   const ush* __restrict__ Bhf,
                                                   float* __restrict__ zpart) {
  __shared__ ush Bs[64 * 512];
  __shared__ float red[2][64];
  const int tid = threadIdx.x;
  const int lane = tid & 63, wid = tid >> 6;
  const int wc2 = wid >> 1, wt = wid & 1;
  const int l15 = lane & 15, g = lane >> 4;
  const int cb = blockIdx.x;
  const int cBase = cb * 64;

  s16x8 afr[2][16];
#pragma unroll
  for (int mi = 0; mi < 2; ++mi) {
    int c = cBase + wc2 * 32 + mi * 16 + l15;
#pragma unroll
    for (int ks = 0; ks < 16; ++ks)
      afr[mi][ks] = *(const s16x8*)&Ahf[(size_t)c * Dn + ks * 32 + g * 8];
  }

  for (int tt = 0; tt < 64; ++tt) {
    const int tBase = tt * 64;
#pragma unroll
    for (int rr = 0; rr < 16; ++rr) {
      int idx = rr * 256 + tid;
      int row = idx >> 6, ch = idx & 63;
      gl16(&Bhf[(size_t)(tBase + row) * Dn + ((ch ^ (row & 7)) << 3)],
           &Bs[rr * 2048 + wid * 512]);
    }
    __syncthreads();
    f32x4 S[2][2];
#pragma unroll
    for (int mi = 0; mi < 2; ++mi)
#pragma unroll
      for (int ni = 0; ni < 2; ++ni) S[mi][ni] = (f32x4){0.f, 0.f, 0.f, 0.f};
#pragma unroll
    for (int ks = 0; ks < 16; ++ks) {
      s16x8 bfr[2];
#pragma unroll
      for (int ni = 0; ni < 2; ++ni) {
        int trow = wt * 32 + ni * 16 + l15;
        bfr[ni] = *(const s16x8*)&Bs[trow * 512 + (((ks * 4 + g) ^ (trow & 7)) * 8)];
      }
#pragma unroll
      for (int mi = 0; mi < 2; ++mi)
#pragma unroll
        for (int ni = 0; ni < 2; ++ni) S[mi][ni] = MFMAH(afr[mi][ks], bfr[ni], S[mi][ni]);
    }
    float tacc[2] = {0.f, 0.f};
#pragma unroll
    for (int mi = 0; mi < 2; ++mi)
#pragma unroll
      for (int ni = 0; ni < 2; ++ni)
#pragma unroll
        for (int r = 0; r < 4; ++r) tacc[ni] += __expf(S[mi][ni][r]);
#pragma unroll
    for (int ni = 0; ni < 2; ++ni) {
      float v = tacc[ni];
      v += __shfl_xor(v, 16);
      v += __shfl_xor(v, 32);
      tacc[ni] = v;
    }
    if (g == 0) {
      red[wc2][wt * 32 + l15] = tacc[0];
      red[wc2][wt * 32 + 16 + l15] = tacc[1];
    }
    __syncthreads();
    if (tid < 64) zpart[(size_t)cb * ROWS + tBase + tid] = red[0][tid] + red[1][tid];
  }
}

__global__ void k_invl(const float* __restrict__ zpart, float* __restrict__ invl) {
  int t = blockIdx.x * 256 + threadIdx.x;
  float s = 0.f;
  for (int cb = 0; cb < 512; ++cb) s += zpart[(size_t)cb * ROWS + t];
  invl[t] = 1.0f / s;
}

// prio[b,c] = comb[b] + 0.1 * sum_t exp(scores[b,t,c]) * invl1[b,t]
// Single-term f16 MFMA. launch_bounds(256,3): ~110 VGPR fits, 3 blocks/CU
// gives extra resident waves to absorb the barrier drain (m114 overlap).
__global__ __launch_bounds__(256, 3) void k_usage(const ush* __restrict__ mhf,
                                                  const ush* __restrict__ khf,
                                                  const float* __restrict__ invl,
                                                  const float* __restrict__ comb,
                                                  float* __restrict__ prio) {
  __shared__ ush Ah[128 * 64], Bh[128 * 64];
  const int tid = threadIdx.x;
  const int lane = tid & 63, w = tid >> 6;
  const int l15 = lane & 15, g = lane >> 4;
  const int cBase = blockIdx.x * 128;
  const int b = blockIdx.y;
  const ush* khb = khf + (size_t)b * Tn * Dn;
  const int r0 = tid >> 3, u0 = tid & 7;
  const int usw = (u0 ^ (r0 & 7)) << 3;

  float uacc[2][4] = {{0.f, 0.f, 0.f, 0.f}, {0.f, 0.f, 0.f, 0.f}};
  for (int tt = 0; tt < 8; ++tt) {
    f32x4 S[2][8];
#pragma unroll
    for (int mi = 0; mi < 2; ++mi)
#pragma unroll
      for (int ni = 0; ni < 8; ++ni) S[mi][ni] = (f32x4){0.f, 0.f, 0.f, 0.f};
    for (int kk = 0; kk < 8; ++kk) {
      __syncthreads();
      {
        size_t a0 = (size_t)(cBase + r0) * Dn + kk * 64 + usw;
        size_t a1 = (size_t)(cBase + r0 + 64) * Dn + kk * 64 + usw;
        gl16(&mhf[a0], &Ah[w * 512]);
        gl16(&mhf[a1], &Ah[4096 + w * 512]);
        size_t b0 = (size_t)(tt * 128 + r0) * Dn + kk * 64 + usw;
        size_t b1 = (size_t)(tt * 128 + r0 + 64) * Dn + kk * 64 + usw;
        gl16(&khb[b0], &Bh[w * 512]);
        gl16(&khb[b1], &Bh[4096 + w * 512]);
      }
      __syncthreads();
#pragma unroll
      for (int ks2 = 0; ks2 < 2; ++ks2) {
        s16x8 ah[2];
#pragma unroll
        for (int mi = 0; mi < 2; ++mi) {
          int crow = w * 32 + mi * 16 + l15;
          ah[mi] = *(const s16x8*)&Ah[crow * 64 + (((ks2 * 4 + g) ^ (crow & 7)) * 8)];
        }
#pragma unroll
        for (int ni = 0; ni < 8; ++ni) {
          int trow = ni * 16 + l15;
          s16x8 bh = *(const s16x8*)&Bh[trow * 64 + (((ks2 * 4 + g) ^ (trow & 7)) * 8)];
#pragma unroll
          for (int mi = 0; mi < 2; ++mi) S[mi][ni] = MFMAH(ah[mi], bh, S[mi][ni]);
        }
      }
    }
#pragma unroll
    for (int ni = 0; ni < 8; ++ni) {
      float il = invl[b * Tn + tt * 128 + ni * 16 + l15];
#pragma unroll
      for (int mi = 0; mi < 2; ++mi)
#pragma unroll
        for (int r = 0; r < 4; ++r) uacc[mi][r] += __expf(S[mi][ni][r]) * il;
    }
  }
#pragma unroll
  for (int mi = 0; mi < 2; ++mi)
#pragma unroll
    for (int r = 0; r < 4; ++r) {
      float v = uacc[mi][r];
      v += __shfl_xor(v, 1);
      v += __shfl_xor(v, 2);
      v += __shfl_xor(v, 4);
      v += __shfl_xor(v, 8);
      if (l15 == 0)
        prio[(size_t)b * CAPn + cBase + w * 32 + mi * 16 + g * 4 + r] =
            comb[b] + 0.1f * v;
    }
}

// rank init: unselected slots get Kn (k_newmem tests r < Kn)
__global__ void k_rankinit(int* __restrict__ rank) {
  rank[blockIdx.x * 256 + threadIdx.x] = Kn;
}

// Per-batch exact top-K selection + stable rank (jax top_k semantics).
__global__ __launch_bounds__(1024) void k_select(const float* __restrict__ prio,
                                                 int* __restrict__ rank) {
  const int b = blockIdx.x;
  const float* p = prio + (size_t)b * CAPn;
  __shared__ int hist[256];
  __shared__ unsigned long long s_pref;
  __shared__ int s_krem;
  __shared__ int s_cnt;
  __shared__ unsigned long long selk[Kn];
  const int tid = threadIdx.x;
  if (tid == 0) { s_pref = 0ull; s_krem = Kn; s_cnt = 0; }

#define KEYOF(c, kk)                                                         \
  {                                                                          \
    unsigned mb_ = __float_as_uint(p[(c)]);                                  \
    mb_ = (mb_ & 0x80000000u) ? ~mb_ : (mb_ | 0x80000000u);                  \
    (kk) = ((unsigned long long)mb_ << 32) | (unsigned)(0xFFFFFFFFu - (c));  \
  }

  __syncthreads();
  for (int pos = 56; pos >= 0; pos -= 8) {
    if (tid < 256) hist[tid] = 0;
    __syncthreads();
    unsigned long long pref = s_pref;
    unsigned long long maskhi = (pos == 56) ? 0ull : (~0ull << (pos + 8));
    for (int c = tid; c < CAPn; c += 1024) {
      unsigned long long k;
      KEYOF(c, k);
      if ((k & maskhi) == pref) atomicAdd(&hist[(int)((k >> pos) & 255)], 1);
    }
    __syncthreads();
    if (tid == 0) {
      int krem = s_krem;
      int d = 255;
      for (;; --d) {
        int h = hist[d];
        if (krem <= h || d == 0) break;
        krem -= h;
      }
      s_pref = pref | ((unsigned long long)d << pos);
      s_krem = krem;
    }
    __syncthreads();
  }
  unsigned long long T = s_pref;  // exact Kn-th largest key
  for (int c = tid; c < CAPn; c += 1024) {
    unsigned long long k;
    KEYOF(c, k);
    if (k >= T) {
      int idx = atomicAdd(&s_cnt, 1);
      selk[idx] = k;
    }
  }
  __syncthreads();
  unsigned long long mine = selk[tid];
  int r = 0;
  for (int j = 0; j < Kn; ++j) r += (selk[j] > mine) ? 1 : 0;
  int c = (int)(0xFFFFFFFFu - (unsigned)(mine & 0xFFFFFFFFull));
  rank[(size_t)b * CAPn + c] = r;
#undef KEYOF
}

// new_mem (bf16) = 0.99*mem + 0.0025 * sum_b (rank_b[c] < K ? values[b, rank_b[c], :] : 0)
__global__ void k_newmem(const float* __restrict__ mem, const float* __restrict__ values,
                         const int* __restrict__ rank, ush* __restrict__ nm) {
  int gid = blockIdx.x * 256 + threadIdx.x;
  int c = gid >> 7;
  int q = (gid & 127) << 2;
  f32x4 m = *(const f32x4*)&mem[(size_t)c * Dn + q];
  f32x4 acc = {0.f, 0.f, 0.f, 0.f};
#pragma unroll
  for (int b = 0; b < Bn; ++b) {
    int r = rank[(size_t)b * CAPn + c];
    if (r < Kn) acc += *(const f32x4*)&values[((size_t)b * Tn + r) * Dn + q];
  }
  f32x4 res = m * MOM + acc * RATE_B;
  s16x4 o;
#pragma unroll
  for (int j = 0; j < 4; ++j) o[j] = (short)bfrn(res[j]);
  *(s16x4*)&nm[(size_t)c * Dn + q] = o;
}

// nmT[d][c] = nm[c][d]
__global__ void k_nmT(const ush* __restrict__ nm, ush* __restrict__ nmT) {
  __shared__ ush tile[64][65];
  int cBase = blockIdx.x * 64, dBase = blockIdx.y * 64;
  int tid = threadIdx.x;
#pragma unroll
  for (int rr = 0; rr < 2; ++rr) {
    int idx = rr * 256 + tid;
    int row = idx >> 3, ch = idx & 7;
    s16x8 v = *(const s16x8*)&nm[(size_t)(cBase + row) * Dn + dBase + ch * 8];
#pragma unroll
    for (int j = 0; j < 8; ++j) tile[row][ch * 8 + j] = (ush)v[j];
  }
  __syncthreads();
#pragma unroll
  for (int rr = 0; rr < 2; ++rr) {
    int idx = rr * 256 + tid;
    int drow = idx >> 3, ch = idx & 7;
    s16x8 v;
#pragma unroll
    for (int j = 0; j < 8; ++j) v[j] = (short)tile[ch * 8 + j][drow];
    *(s16x8*)&nmT[(size_t)(dBase + drow) * CAPn + cBase + ch * 8] = v;
  }
}

// Fused attn (round-7/9 version, 431 us, proven): counted-vmcnt pipeline,
// WAR-safe (stage issued post-BAR). Grid (8 cy, 32 qt), 8 waves, Q in regs.
// LDS 131KB: Ms[3][128][64] @0, Mt[3][128][64] @24576, Ps[128][128] @49152.
#define WAITV2 asm volatile("s_waitcnt vmcnt(2)" ::: "memory")
#define WAITL0 asm volatile("s_waitcnt lgkmcnt(0)" ::: "memory")
#define BAR __builtin_amdgcn_s_barrier()
__global__ __launch_bounds__(512, 1) void k_attnout(
    const float* __restrict__ query, const ush* __restrict__ nm,
    const ush* __restrict__ nmT, ush* __restrict__ opart,
    float* __restrict__ zp2) {
  __shared__ ush lds[65536];
  __shared__ float zred[128];
  __shared__ float zacc[128];
  constexpr int LMS = 0, LMT = 24576, LPS = 49152;
  const int tid = threadIdx.x;
  const int lane = tid & 63, w = tid >> 6;
  const int l15 = lane & 15, g = lane >> 4;
  const int cy = blockIdx.x;
  const int qBase = blockIdx.y * 128;
  const int q = w * 16 + l15;
  const int r0 = tid >> 3, u0 = tid & 7;
  const int usw = (u0 ^ (r0 & 7)) << 3;

  auto stage_ms = [&](int buf, int cb_, int kk) {
    const ush* src = nm + (size_t)cb_ * Dn + kk * 64;
    gl16(&src[(size_t)r0 * Dn + usw], &lds[LMS + buf * 8192 + w * 512]);
    gl16(&src[(size_t)(r0 + 64) * Dn + usw], &lds[LMS + buf * 8192 + 4096 + w * 512]);
  };
  auto stage_mt = [&](int buf, int cb_, int u) {
    const ush* src = nmT + (size_t)((u >> 1) * 128) * CAPn + cb_ + (u & 1) * 64;
    gl16(&src[(size_t)r0 * CAPn + usw], &lds[LMT + buf * 8192 + w * 512]);
    gl16(&src[(size_t)(r0 + 64) * CAPn + usw], &lds[LMT + buf * 8192 + 4096 + w * 512]);
  };

  s16x8 qfr[16];
  {
    const float* qsrc = query + (size_t)(qBase + q) * Dn;
#pragma unroll
    for (int ks = 0; ks < 16; ++ks) {
      f32x4 a = *(const f32x4*)&qsrc[ks * 32 + g * 8];
      f32x4 b = *(const f32x4*)&qsrc[ks * 32 + g * 8 + 4];
      s16x8 h;
#pragma unroll
      for (int j = 0; j < 4; ++j) {
        h[j] = (short)bfrn(a[j]);
        h[4 + j] = (short)bfrn(b[j]);
      }
      qfr[ks] = h;
    }
  }

  f32x4 O[32];
#pragma unroll
  for (int i = 0; i < 32; ++i) O[i] = (f32x4){0.f, 0.f, 0.f, 0.f};
  if (tid < 128) zacc[tid] = 0.f;

  stage_ms(0, cy * 4096, 0);
  stage_ms(1, cy * 4096, 1);

  for (int ct = 0; ct < 32; ++ct) {
    const int cBase = cy * 4096 + ct * 128;
    const int cNext = cy * 4096 + ((ct + 1) & 31) * 128;

    f32x4 S[8];
#pragma unroll
    for (int i = 0; i < 8; ++i) S[i] = (f32x4){0.f, 0.f, 0.f, 0.f};
#pragma unroll
    for (int kk = 0; kk < 8; ++kk) {
      WAITV2;
      WAITL0;
      BAR;
      if (kk < 6) stage_ms((kk + 2) % 3, cBase, kk + 2);
      else if (kk == 6) stage_mt(0, cBase, 0);
      else stage_mt(1, cBase, 1);
      __builtin_amdgcn_s_setprio(1);
#pragma unroll
      for (int ks2 = 0; ks2 < 2; ++ks2) {
#pragma unroll
        for (int mi = 0; mi < 8; ++mi) {
          int row = mi * 16 + l15;
          s16x8 am = *(const s16x8*)&lds[LMS + (kk % 3) * 8192 + row * 64 +
                                         (((ks2 * 4 + g) ^ (row & 7)) << 3)];
          S[mi] = MFMA(am, qfr[kk * 2 + ks2], S[mi]);
        }
      }
      __builtin_amdgcn_s_setprio(0);
    }

    float zl = 0.f;
#pragma unroll
    for (int mi = 0; mi < 8; ++mi) {
      s16x4 p;
#pragma unroll
      for (int r = 0; r < 4; ++r) {
        float e = __expf(S[mi][r] * SCALE);
        zl += e;
        p[r] = (short)bfrn(e);
      }
      int u16 = (mi * 2 + (g >> 1)) ^ l15;
      *(s16x4*)&lds[LPS + q * 128 + u16 * 8 + (g & 1) * 4] = p;
    }
    zl += __shfl_xor(zl, 16);
    zl += __shfl_xor(zl, 32);
    if (g == 0) zred[q] = zl;
    WAITL0;
    BAR;
    if (tid < 128) zacc[tid] += zred[tid];

#pragma unroll
    for (int u = 0; u < 8; ++u) {
      WAITV2;
      WAITL0;
      BAR;
      if (u < 6) stage_mt((u + 2) % 3, cBase, u + 2);
      else if (u == 6) stage_ms(0, cNext, 0);
      else stage_ms(1, cNext, 1);
      __builtin_amdgcn_s_setprio(1);
      const int hh = u & 1;
#pragma unroll
      for (int kc = 0; kc < 2; ++kc) {
        int u16 = (hh * 8 + kc * 4 + g) ^ l15;
        s16x8 pb = *(const s16x8*)&lds[LPS + q * 128 + u16 * 8];
#pragma unroll
        for (int mi = 0; mi < 8; ++mi) {
          int row = mi * 16 + l15;
          s16x8 am = *(const s16x8*)&lds[LMT + (u % 3) * 8192 + row * 64 +
                                         (((kc * 4 + g) ^ (row & 7)) << 3)];
          O[(u >> 1) * 8 + mi] = MFMA(am, pb, O[(u >> 1) * 8 + mi]);
        }
      }
      __builtin_amdgcn_s_setprio(0);
    }
  }

  __syncthreads();
  if (tid < 128) zp2[(size_t)cy * ROWS + qBase + tid] = zacc[tid];
#pragma unroll
  for (int ds = 0; ds < 4; ++ds) {
    __syncthreads();
#pragma unroll
    for (int mi = 0; mi < 8; ++mi) {
      s16x4 ov;
#pragma unroll
      for (int r = 0; r < 4; ++r) ov[r] = (short)bfrn(O[ds * 8 + mi][r]);
      int u16 = (mi * 2 + (g >> 1)) ^ l15;
      *(s16x4*)&lds[LPS + q * 128 + u16 * 8 + (g & 1) * 4] = ov;
    }
    __syncthreads();
#pragma unroll
    for (int i = 0; i < 4; ++i) {
      int slot = i * 512 + tid;
      int qq = slot >> 4, u16 = slot & 15;
      s16x8 v = *(const s16x8*)&lds[LPS + qq * 128 + ((u16 ^ (qq & 15)) << 3)];
      *(s16x8*)&opart[((size_t)cy * ROWS + qBase + qq) * Dn + ds * 128 + u16 * 8] = v;
    }
  }
}

// out = (sum_cy opart[cy]) / (sum_cy zp2[cy]) per row
__global__ void k_merge(const ush* __restrict__ opart, const float* __restrict__ zp2,
                        float* __restrict__ out) {
  size_t i = ((size_t)blockIdx.x * 256 + threadIdx.x) * 4;
  int row = (int)(i >> 9);
  float z = 0.f;
#pragma unroll
  for (int cyy = 0; cyy < 8; ++cyy) z += zp2[(size_t)cyy * ROWS + row];
  float inv = 1.0f / z;
  f32x4 acc = {0.f, 0.f, 0.f, 0.f};
#pragma unroll
  for (int cyy = 0; cyy < 8; ++cyy) {
    s16x4 a = *(const s16x4*)&opart[(size_t)cyy * ROWS * Dn + i];
#pragma unroll
    for (int j = 0; j < 4; ++j) acc[j] += bff((ush)a[j]);
  }
#pragma unroll
  for (int j = 0; j < 4; ++j) acc[j] *= inv;
  *(f32x4*)&out[i] = acc;
}

extern "C" void kernel_launch(void* const* d_in, const int* in_sizes, int n_in,
                              void* d_out, int out_size, void* d_ws, size_t ws_size,
                              hipStream_t stream) {
  const float* keys = (const float*)d_in[0];
  const float* values = (const float*)d_in[1];
  const float* importance = (const float*)d_in[2];
  const float* query = (const float*)d_in[3];
  const float* mem = (const float*)d_in[4];
  char* wsb = (char*)d_ws;
  ush* nm    = (ush*)(wsb + OFF_NM);
  ush* nmT   = (ush*)(wsb + OFF_NMT);
  ush* mhf   = (ush*)(wsb + OFF_NMT);  // alias (dead after k_usage; nmT written later)
  ush* khf   = (ush*)(wsb + OFF_KHF);
  ush* opart = (ush*)(wsb + OFF_OPART);
  float* zpart = (float*)(wsb + OFF_ZPART);
  float* prio  = (float*)(wsb + OFF_PRIO);
  int* rank    = (int*)(wsb + OFF_RANK);
  float* comb  = (float*)(wsb + OFF_COMB);
  float* zp2   = (float*)(wsb + OFF_ZP2);
  float* invl1 = (float*)(wsb + OFF_COMB + 64);
  float* out = (float*)d_out;

  k_combined<<<Bn, 256, 0, stream>>>(importance, comb);
  k_cvt_f16<<<(ROWS * Dn / 4) / 256, 256, 0, stream>>>(keys, khf);
  k_cvt_f16<<<(CAPn * Dn / 4) / 256, 256, 0, stream>>>(mem, mhf);
  k_rowexp<<<CAPn / 64, 256, 0, stream>>>(mhf, khf, zpart);
  k_invl<<<ROWS / 256, 256, 0, stream>>>(zpart, invl1);
  k_usage<<<dim3(CAPn / 128, Bn), 256, 0, stream>>>(mhf, khf, invl1, comb, prio);
  k_rankinit<<<(Bn * CAPn) / 256, 256, 0, stream>>>(rank);
  k_select<<<Bn, 1024, 0, stream>>>(prio, rank);
  k_newmem<<<(CAPn * Dn / 4) / 256, 256, 0, stream>>>(mem, values, rank, nm);
  k_nmT<<<dim3(CAPn / 64, Dn / 64), 256, 0, stream>>>(nm, nmT);
  k_attnout<<<dim3(8, ROWS / 128), 512, 0, stream>>>(query, nm, nmT, opart, zp2);
  k_merge<<<(ROWS * Dn / 4) / 256, 256, 0, stream>>>(opart, zp2, out);
}

// Round 12
// 857.437 us; speedup vs baseline: 1.6407x; 1.1187x over previous
//
#include <hip/hip_runtime.h>
#include <hip/hip_fp8.h>

typedef float f32x4 __attribute__((ext_vector_type(4)));
typedef short s16x8 __attribute__((ext_vector_type(8)));
typedef short s16x4 __attribute__((ext_vector_type(4)));
typedef unsigned short ush;
typedef unsigned char u8;

constexpr int Bn = 4, Tn = 1024, Dn = 512, CAPn = 32768, Kn = 1024;
constexpr int ROWS = Bn * Tn; // 4096
constexpr float SCALE = 0.044194173824159216f; // 1/sqrt(512)
constexpr float SC64 = SCALE / 64.0f;          // nm8 stored as 64*new_mem
constexpr float MOM = 0.99f;
constexpr float RATE_B = 0.0025f; // 0.01 / B

// ---- workspace layout (byte offsets). ws proven >= 102.0e6 B ----
constexpr size_t OFF_NM8   = 0;                      // fp8 [CAP][D] (late) 16.78M
constexpr size_t OFF_NMT   = 33554432;               // bf16 [D][CAP] (alias: mem f16 early)
constexpr size_t OFF_OPART = 67108864;               // bf16 [8][ROWS][D] (late)  -- UNION with:
constexpr size_t OFF_KHF   = 67108864;               //   f16 [ROWS][D] (early)
constexpr size_t OFF_ZPART = 75497472;               //   f32 [512][ROWS] (early)
constexpr size_t OFF_PRIO  = 83886080;               //   f32 [4][CAP] (early)
constexpr size_t OFF_RANK  = 84410368;               //   i32 [4][CAP] (early)
constexpr size_t OFF_COMB  = 84934656;               //   f32 [4] (early; +64: invl1)
constexpr size_t OFF_ZP2   = 100663296;              // f32 [8][ROWS] (late)

#define MFMA(a, b, c) __builtin_amdgcn_mfma_f32_16x16x32_bf16((a), (b), (c), 0, 0, 0)
#define MFMAH(a, b, c) __builtin_amdgcn_mfma_f32_16x16x32_f16((a), (b), (c), 0, 0, 0)
#define MFMA8(a, b, c) __builtin_amdgcn_mfma_f32_16x16x32_fp8_fp8((a), (b), (c), 0, 0, 0)

__device__ __forceinline__ ush bfrn(float x) {
  unsigned u = __float_as_uint(x);
  return (ush)((u + 0x7FFFu + ((u >> 16) & 1u)) >> 16);
}
__device__ __forceinline__ float bff(ush h) { return __uint_as_float(((unsigned)h) << 16); }
__device__ __forceinline__ ush f16rn(float x) {
  _Float16 h = (_Float16)x;  // v_cvt_f16_f32, RTN
  return *(ush*)&h;
}
__device__ __forceinline__ u8 f8rn(float x) {
  __hip_fp8_e4m3 v(x);
  return (u8)v.__x;
}

__device__ __forceinline__ void gl16(const void* g, void* l) {
  __builtin_amdgcn_global_load_lds(
      (const __attribute__((address_space(1))) void*)(uintptr_t)g,
      (__attribute__((address_space(3))) void*)(uintptr_t)l, 16, 0, 0);
}

// combined[b] = mean(importance[b,:,0])
__global__ void k_combined(const float* __restrict__ imp, float* __restrict__ comb) {
  __shared__ float red[256];
  int b = blockIdx.x;
  float s = 0.f;
  for (int t = threadIdx.x; t < Tn; t += 256) s += imp[(size_t)b * Tn + t];
  red[threadIdx.x] = s;
  __syncthreads();
  for (int off = 128; off > 0; off >>= 1) {
    if (threadIdx.x < (unsigned)off) red[threadIdx.x] += red[threadIdx.x + off];
    __syncthreads();
  }
  if (threadIdx.x == 0) comb[b] = red[0] * (1.0f / Tn);
}

// x -> f16 (RTN). 4 elems/thread.
__global__ void k_cvt_f16(const float* __restrict__ x, ush* __restrict__ o) {
  size_t i = ((size_t)blockIdx.x * 256 + threadIdx.x) * 4;
  f32x4 v = *(const f32x4*)&x[i];
  s16x4 h;
#pragma unroll
  for (int j = 0; j < 4; ++j) h[j] = (short)f16rn(v[j]);
  *(s16x4*)&o[i] = h;
}

// Z partials: zpart[cb][t] = sum over this block's 64 c of exp(A[c,:].B[t,:])
__global__ __launch_bounds__(256, 2) void k_rowexp(const ush* __restrict__ Ahf,
                                                   const ush* __restrict__ Bhf,
                                                   float* __restrict__ zpart) {
  __shared__ ush Bs[64 * 512];
  __shared__ float red[2][64];
  const int tid = threadIdx.x;
  const int lane = tid & 63, wid = tid >> 6;
  const int wc2 = wid >> 1, wt = wid & 1;
  const int l15 = lane & 15, g = lane >> 4;
  const int cb = blockIdx.x;
  const int cBase = cb * 64;

  s16x8 afr[2][16];
#pragma unroll
  for (int mi = 0; mi < 2; ++mi) {
    int c = cBase + wc2 * 32 + mi * 16 + l15;
#pragma unroll
    for (int ks = 0; ks < 16; ++ks)
      afr[mi][ks] = *(const s16x8*)&Ahf[(size_t)c * Dn + ks * 32 + g * 8];
  }

  for (int tt = 0; tt < 64; ++tt) {
    const int tBase = tt * 64;
#pragma unroll
    for (int rr = 0; rr < 16; ++rr) {
      int idx = rr * 256 + tid;
      int row = idx >> 6, ch = idx & 63;
      gl16(&Bhf[(size_t)(tBase + row) * Dn + ((ch ^ (row & 7)) << 3)],
           &Bs[rr * 2048 + wid * 512]);
    }
    __syncthreads();
    f32x4 S[2][2];
#pragma unroll
    for (int mi = 0; mi < 2; ++mi)
#pragma unroll
      for (int ni = 0; ni < 2; ++ni) S[mi][ni] = (f32x4){0.f, 0.f, 0.f, 0.f};
#pragma unroll
    for (int ks = 0; ks < 16; ++ks) {
      s16x8 bfr[2];
#pragma unroll
      for (int ni = 0; ni < 2; ++ni) {
        int trow = wt * 32 + ni * 16 + l15;
        bfr[ni] = *(const s16x8*)&Bs[trow * 512 + (((ks * 4 + g) ^ (trow & 7)) * 8)];
      }
#pragma unroll
      for (int mi = 0; mi < 2; ++mi)
#pragma unroll
        for (int ni = 0; ni < 2; ++ni) S[mi][ni] = MFMAH(afr[mi][ks], bfr[ni], S[mi][ni]);
    }
    float tacc[2] = {0.f, 0.f};
#pragma unroll
    for (int mi = 0; mi < 2; ++mi)
#pragma unroll
      for (int ni = 0; ni < 2; ++ni)
#pragma unroll
        for (int r = 0; r < 4; ++r) tacc[ni] += __expf(S[mi][ni][r]);
#pragma unroll
    for (int ni = 0; ni < 2; ++ni) {
      float v = tacc[ni];
      v += __shfl_xor(v, 16);
      v += __shfl_xor(v, 32);
      tacc[ni] = v;
    }
    if (g == 0) {
      red[wc2][wt * 32 + l15] = tacc[0];
      red[wc2][wt * 32 + 16 + l15] = tacc[1];
    }
    __syncthreads();
    if (tid < 64) zpart[(size_t)cb * ROWS + tBase + tid] = red[0][tid] + red[1][tid];
  }
}

__global__ void k_invl(const float* __restrict__ zpart, float* __restrict__ invl) {
  int t = blockIdx.x * 256 + threadIdx.x;
  float s = 0.f;
  for (int cb = 0; cb < 512; ++cb) s += zpart[(size_t)cb * ROWS + t];
  invl[t] = 1.0f / s;
}

// prio[b,c] = comb[b] + 0.1 * sum_t exp(scores[b,t,c]) * invl1[b,t]
__global__ __launch_bounds__(256, 3) void k_usage(const ush* __restrict__ mhf,
                                                  const ush* __restrict__ khf,
                                                  const float* __restrict__ invl,
                                                  const float* __restrict__ comb,
                                                  float* __restrict__ prio) {
  __shared__ ush Ah[128 * 64], Bh[128 * 64];
  const int tid = threadIdx.x;
  const int lane = tid & 63, w = tid >> 6;
  const int l15 = lane & 15, g = lane >> 4;
  const int cBase = blockIdx.x * 128;
  const int b = blockIdx.y;
  const ush* khb = khf + (size_t)b * Tn * Dn;
  const int r0 = tid >> 3, u0 = tid & 7;
  const int usw = (u0 ^ (r0 & 7)) << 3;

  float uacc[2][4] = {{0.f, 0.f, 0.f, 0.f}, {0.f, 0.f, 0.f, 0.f}};
  for (int tt = 0; tt < 8; ++tt) {
    f32x4 S[2][8];
#pragma unroll
    for (int mi = 0; mi < 2; ++mi)
#pragma unroll
      for (int ni = 0; ni < 8; ++ni) S[mi][ni] = (f32x4){0.f, 0.f, 0.f, 0.f};
    for (int kk = 0; kk < 8; ++kk) {
      __syncthreads();
      {
        size_t a0 = (size_t)(cBase + r0) * Dn + kk * 64 + usw;
        size_t a1 = (size_t)(cBase + r0 + 64) * Dn + kk * 64 + usw;
        gl16(&mhf[a0], &Ah[w * 512]);
        gl16(&mhf[a1], &Ah[4096 + w * 512]);
        size_t b0 = (size_t)(tt * 128 + r0) * Dn + kk * 64 + usw;
        size_t b1 = (size_t)(tt * 128 + r0 + 64) * Dn + kk * 64 + usw;
        gl16(&khb[b0], &Bh[w * 512]);
        gl16(&khb[b1], &Bh[4096 + w * 512]);
      }
      __syncthreads();
#pragma unroll
      for (int ks2 = 0; ks2 < 2; ++ks2) {
        s16x8 ah[2];
#pragma unroll
        for (int mi = 0; mi < 2; ++mi) {
          int crow = w * 32 + mi * 16 + l15;
          ah[mi] = *(const s16x8*)&Ah[crow * 64 + (((ks2 * 4 + g) ^ (crow & 7)) * 8)];
        }
#pragma unroll
        for (int ni = 0; ni < 8; ++ni) {
          int trow = ni * 16 + l15;
          s16x8 bh = *(const s16x8*)&Bh[trow * 64 + (((ks2 * 4 + g) ^ (trow & 7)) * 8)];
#pragma unroll
          for (int mi = 0; mi < 2; ++mi) S[mi][ni] = MFMAH(ah[mi], bh, S[mi][ni]);
        }
      }
    }
#pragma unroll
    for (int ni = 0; ni < 8; ++ni) {
      float il = invl[b * Tn + tt * 128 + ni * 16 + l15];
#pragma unroll
      for (int mi = 0; mi < 2; ++mi)
#pragma unroll
        for (int r = 0; r < 4; ++r) uacc[mi][r] += __expf(S[mi][ni][r]) * il;
    }
  }
#pragma unroll
  for (int mi = 0; mi < 2; ++mi)
#pragma unroll
    for (int r = 0; r < 4; ++r) {
      float v = uacc[mi][r];
      v += __shfl_xor(v, 1);
      v += __shfl_xor(v, 2);
      v += __shfl_xor(v, 4);
      v += __shfl_xor(v, 8);
      if (l15 == 0)
        prio[(size_t)b * CAPn + cBase + w * 32 + mi * 16 + g * 4 + r] =
            comb[b] + 0.1f * v;
    }
}

// rank init: unselected slots get Kn
__global__ void k_rankinit(int* __restrict__ rank) {
  rank[blockIdx.x * 256 + threadIdx.x] = Kn;
}

// Per-batch exact top-K selection + stable rank (jax top_k semantics).
__global__ __launch_bounds__(1024) void k_select(const float* __restrict__ prio,
                                                 int* __restrict__ rank) {
  const int b = blockIdx.x;
  const float* p = prio + (size_t)b * CAPn;
  __shared__ int hist[256];
  __shared__ unsigned long long s_pref;
  __shared__ int s_krem;
  __shared__ int s_cnt;
  __shared__ unsigned long long selk[Kn];
  const int tid = threadIdx.x;
  if (tid == 0) { s_pref = 0ull; s_krem = Kn; s_cnt = 0; }

#define KEYOF(c, kk)                                                         \
  {                                                                          \
    unsigned mb_ = __float_as_uint(p[(c)]);                                  \
    mb_ = (mb_ & 0x80000000u) ? ~mb_ : (mb_ | 0x80000000u);                  \
    (kk) = ((unsigned long long)mb_ << 32) | (unsigned)(0xFFFFFFFFu - (c));  \
  }

  __syncthreads();
  for (int pos = 56; pos >= 0; pos -= 8) {
    if (tid < 256) hist[tid] = 0;
    __syncthreads();
    unsigned long long pref = s_pref;
    unsigned long long maskhi = (pos == 56) ? 0ull : (~0ull << (pos + 8));
    for (int c = tid; c < CAPn; c += 1024) {
      unsigned long long k;
      KEYOF(c, k);
      if ((k & maskhi) == pref) atomicAdd(&hist[(int)((k >> pos) & 255)], 1);
    }
    __syncthreads();
    if (tid == 0) {
      int krem = s_krem;
      int d = 255;
      for (;; --d) {
        int h = hist[d];
        if (krem <= h || d == 0) break;
        krem -= h;
      }
      s_pref = pref | ((unsigned long long)d << pos);
      s_krem = krem;
    }
    __syncthreads();
  }
  unsigned long long T = s_pref;  // exact Kn-th largest key
  for (int c = tid; c < CAPn; c += 1024) {
    unsigned long long k;
    KEYOF(c, k);
    if (k >= T) {
      int idx = atomicAdd(&s_cnt, 1);
      selk[idx] = k;
    }
  }
  __syncthreads();
  unsigned long long mine = selk[tid];
  int r = 0;
  for (int j = 0; j < Kn; ++j) r += (selk[j] > mine) ? 1 : 0;
  int c = (int)(0xFFFFFFFFu - (unsigned)(mine & 0xFFFFFFFFull));
  rank[(size_t)b * CAPn + c] = r;
#undef KEYOF
}

// nm8 (fp8 e4m3) = 64 * (0.99*mem + 0.0025*sum_b selected values)   [r10-proven]
__global__ void k_newmem8(const float* __restrict__ mem, const float* __restrict__ values,
                          const int* __restrict__ rank, u8* __restrict__ nm8) {
  int gid = blockIdx.x * 256 + threadIdx.x;
  int c = gid >> 7;
  int q = (gid & 127) << 2;
  f32x4 m = *(const f32x4*)&mem[(size_t)c * Dn + q];
  f32x4 acc = {0.f, 0.f, 0.f, 0.f};
#pragma unroll
  for (int b = 0; b < Bn; ++b) {
    int r = rank[(size_t)b * CAPn + c];
    if (r < Kn) acc += *(const f32x4*)&values[((size_t)b * Tn + r) * Dn + q];
  }
  f32x4 res = (m * MOM + acc * RATE_B) * 64.0f;
  union { u8 b[4]; unsigned w; } out;
#pragma unroll
  for (int j = 0; j < 4; ++j) out.b[j] = f8rn(res[j]);
  *(unsigned*)&nm8[(size_t)c * Dn + q] = out.w;
}

// nmT[d][c] = new_mem[c][d] (bf16), recomputed from mem/values/rank. [r10-proven]
__global__ __launch_bounds__(256) void k_nmT(const float* __restrict__ mem,
                                             const float* __restrict__ values,
                                             const int* __restrict__ rank,
                                             ush* __restrict__ nmT) {
  __shared__ ush tile[64][65];
  int cBase = blockIdx.x * 64, dBase = blockIdx.y * 64;
  int tid = threadIdx.x;
  int c = tid >> 2, dq = (tid & 3) * 16;
  int rr[4];
#pragma unroll
  for (int b = 0; b < Bn; ++b) rr[b] = rank[(size_t)b * CAPn + cBase + c];
#pragma unroll
  for (int j = 0; j < 4; ++j) {
    f32x4 m = *(const f32x4*)&mem[(size_t)(cBase + c) * Dn + dBase + dq + j * 4];
    f32x4 a = {0.f, 0.f, 0.f, 0.f};
#pragma unroll
    for (int b = 0; b < Bn; ++b)
      if (rr[b] < Kn)
        a += *(const f32x4*)&values[((size_t)b * Tn + rr[b]) * Dn + dBase + dq + j * 4];
    f32x4 res = m * MOM + a * RATE_B;
#pragma unroll
    for (int jj = 0; jj < 4; ++jj) tile[c][dq + j * 4 + jj] = bfrn(res[jj]);
  }
  __syncthreads();
  int drow = tid >> 2, cq = (tid & 3) * 16;
#pragma unroll
  for (int k = 0; k < 2; ++k) {
    s16x8 v;
#pragma unroll
    for (int j = 0; j < 8; ++j) v[j] = (short)tile[cq + k * 8 + j][drow];
    *(s16x8*)&nmT[(size_t)(dBase + drow) * CAPn + cBase + cq + k * 8] = v;
  }
}

// Fused attn: r7 pipeline/staging structure, QK ported to fp8 (16x16x32_fp8_fp8).
// Grid (8 cy, 32 qt), 8 waves, Q fp8 in regs. 13 phases/ct (4 QK + P + 8 PV).
// Counted vmcnt(2) (each phase stages one 2-gl16 pair), WAR-safe post-BAR staging.
// LDS bytes: Ms8[3][128c][128k-fp8] 48KB @0; Mt[3][128][64] bf16 48KB @49152;
//            Ps[128q][128c] bf16 32KB @98304. (+zred/zacc)
#define WAITV2 asm volatile("s_waitcnt vmcnt(2)" ::: "memory")
#define WAITL0 asm volatile("s_waitcnt lgkmcnt(0)" ::: "memory")
#define BAR __builtin_amdgcn_s_barrier()
__global__ __launch_bounds__(512, 1) void k_attnout(
    const float* __restrict__ query, const u8* __restrict__ nm8,
    const ush* __restrict__ nmT, ush* __restrict__ opart,
    float* __restrict__ zp2) {
  __shared__ __align__(16) u8 L[131072];
  __shared__ float zred[128];
  __shared__ float zacc[128];
  constexpr int LMS = 0, LMT = 49152, LPS = 98304;  // byte offsets
  const int tid = threadIdx.x;
  const int lane = tid & 63, w = tid >> 6;
  const int l15 = lane & 15, g = lane >> 4;
  const int cy = blockIdx.x;
  const int qBase = blockIdx.y * 128;
  const int q = w * 16 + l15;
  const int r0 = tid >> 3, u0 = tid & 7;
  const int usw = (u0 ^ (r0 & 7)) << 3;   // ush units (nmT staging, 128B rows)
  const int usw8 = (u0 ^ (r0 & 7)) << 4;  // bytes (nm8 staging, 128B rows)

  auto stage_ms = [&](int buf, int cb_, int kk) {
    const u8* src = nm8 + (size_t)cb_ * Dn + kk * 128;
    gl16(&src[(size_t)r0 * Dn + usw8], &L[LMS + buf * 16384 + w * 1024]);
    gl16(&src[(size_t)(r0 + 64) * Dn + usw8], &L[LMS + buf * 16384 + 8192 + w * 1024]);
  };
  auto stage_mt = [&](int buf, int cb_, int u) {
    const ush* src = nmT + (size_t)((u >> 1) * 128) * CAPn + cb_ + (u & 1) * 64;
    gl16(&src[(size_t)r0 * CAPn + usw], &L[LMT + buf * 16384 + w * 1024]);
    gl16(&src[(size_t)(r0 + 64) * CAPn + usw], &L[LMT + buf * 16384 + 8192 + w * 1024]);
  };

  // Q fp8 fragments in registers: row qBase+q, K=512 as 16 chunks of 32.
  // B-frag (16x16x32 fp8): col=lane&15, k=(lane>>4)*8+j -> 8 consecutive fp8.
  long qfr8[16];
  {
    const float* qsrc = query + (size_t)(qBase + q) * Dn;
#pragma unroll
    for (int ks = 0; ks < 16; ++ks) {
      f32x4 a = *(const f32x4*)&qsrc[ks * 32 + g * 8];
      f32x4 b = *(const f32x4*)&qsrc[ks * 32 + g * 8 + 4];
      union { u8 c[8]; long l; } u;
#pragma unroll
      for (int j = 0; j < 4; ++j) {
        u.c[j] = f8rn(a[j]);
        u.c[4 + j] = f8rn(b[j]);
      }
      qfr8[ks] = u.l;
    }
  }

  f32x4 O[32];
#pragma unroll
  for (int i = 0; i < 32; ++i) O[i] = (f32x4){0.f, 0.f, 0.f, 0.f};
  if (tid < 128) zacc[tid] = 0.f;

  stage_ms(0, cy * 4096, 0);
  stage_ms(1, cy * 4096, 1);

  for (int ct = 0; ct < 32; ++ct) {
    const int cBase = cy * 4096 + ct * 128;
    const int cNext = cy * 4096 + ((ct + 1) & 31) * 128;

    // ---- QK phases kk=0..3 (K-chunks of 128 fp8): consume Ms[kk%3] ----
    f32x4 S[8];
#pragma unroll
    for (int i = 0; i < 8; ++i) S[i] = (f32x4){0.f, 0.f, 0.f, 0.f};
#pragma unroll
    for (int kk = 0; kk < 4; ++kk) {
      WAITV2;
      WAITL0;
      BAR;
      if (kk < 2) stage_ms((kk + 2) % 3, cBase, kk + 2);
      else if (kk == 2) stage_mt(0, cBase, 0);
      else stage_mt(1, cBase, 1);
      __builtin_amdgcn_s_setprio(1);
#pragma unroll
      for (int ks = 0; ks < 4; ++ks) {
#pragma unroll
        for (int mi = 0; mi < 8; ++mi) {
          int row = mi * 16 + l15;
          long a = *(const long*)&L[LMS + (kk % 3) * 16384 + row * 128 +
                                    (((ks * 2 + (g >> 1)) ^ (row & 7)) << 4) +
                                    (g & 1) * 8];
          S[mi] = MFMA8(a, qfr8[kk * 4 + ks], S[mi]);
        }
      }
      __builtin_amdgcn_s_setprio(0);
    }

    // ---- P phase: exp(S*SC64) -> Ps (unnormalized); z partial. No stage. ----
    float zl = 0.f;
#pragma unroll
    for (int mi = 0; mi < 8; ++mi) {
      s16x4 p;
#pragma unroll
      for (int r = 0; r < 4; ++r) {
        float e = __expf(S[mi][r] * SC64);
        zl += e;
        p[r] = (short)bfrn(e);
      }
      int u16 = (mi * 2 + (g >> 1)) ^ l15;
      *(s16x4*)&L[LPS + q * 256 + u16 * 16 + (g & 1) * 8] = p;
    }
    zl += __shfl_xor(zl, 16);
    zl += __shfl_xor(zl, 32);
    if (g == 0) zred[q] = zl;
    WAITL0;
    BAR;
    if (tid < 128) zacc[tid] += zred[tid];

    // ---- PV phases u=0..7 (byte-identical to r7, bf16) ----
#pragma unroll
    for (int u = 0; u < 8; ++u) {
      WAITV2;
      WAITL0;
      BAR;
      if (u < 6) stage_mt((u + 2) % 3, cBase, u + 2);
      else if (u == 6) stage_ms(0, cNext, 0);
      else stage_ms(1, cNext, 1);
      __builtin_amdgcn_s_setprio(1);
      const int hh = u & 1;
#pragma unroll
      for (int kc = 0; kc < 2; ++kc) {
        int u16 = (hh * 8 + kc * 4 + g) ^ l15;
        s16x8 pb = *(const s16x8*)&L[LPS + q * 256 + u16 * 16];
#pragma unroll
        for (int mi = 0; mi < 8; ++mi) {
          int row = mi * 16 + l15;
          s16x8 am = *(const s16x8*)&L[LMT + (u % 3) * 16384 + row * 128 +
                                       (((kc * 4 + g) ^ (row & 7)) << 4)];
          O[(u >> 1) * 8 + mi] = MFMA(am, pb, O[(u >> 1) * 8 + mi]);
        }
      }
      __builtin_amdgcn_s_setprio(0);
    }
  }

  // ---- epilogue: drain, z store, O transpose via Ps region ----
  __syncthreads();
  if (tid < 128) zp2[(size_t)cy * ROWS + qBase + tid] = zacc[tid];
#pragma unroll
  for (int ds = 0; ds < 4; ++ds) {
    __syncthreads();
#pragma unroll
    for (int mi = 0; mi < 8; ++mi) {
      s16x4 ov;
#pragma unroll
      for (int r = 0; r < 4; ++r) ov[r] = (short)bfrn(O[ds * 8 + mi][r]);
      int u16 = (mi * 2 + (g >> 1)) ^ l15;
      *(s16x4*)&L[LPS + q * 256 + u16 * 16 + (g & 1) * 8] = ov;
    }
    __syncthreads();
#pragma unroll
    for (int i = 0; i < 4; ++i) {
      int slot = i * 512 + tid;
      int qq = slot >> 4, u16 = slot & 15;
      s16x8 v = *(const s16x8*)&L[LPS + qq * 256 + ((u16 ^ (qq & 15)) << 4)];
      *(s16x8*)&opart[((size_t)cy * ROWS + qBase + qq) * Dn + ds * 128 + u16 * 8] = v;
    }
  }
}

// out = (sum_cy opart[cy]) / (sum_cy zp2[cy]) per row
__global__ void k_merge(const ush* __restrict__ opart, const float* __restrict__ zp2,
                        float* __restrict__ out) {
  size_t i = ((size_t)blockIdx.x * 256 + threadIdx.x) * 4;
  int row = (int)(i >> 9);
  float z = 0.f;
#pragma unroll
  for (int cyy = 0; cyy < 8; ++cyy) z += zp2[(size_t)cyy * ROWS + row];
  float inv = 1.0f / z;
  f32x4 acc = {0.f, 0.f, 0.f, 0.f};
#pragma unroll
  for (int cyy = 0; cyy < 8; ++cyy) {
    s16x4 a = *(const s16x4*)&opart[(size_t)cyy * ROWS * Dn + i];
#pragma unroll
    for (int j = 0; j < 4; ++j) acc[j] += bff((ush)a[j]);
  }
#pragma unroll
  for (int j = 0; j < 4; ++j) acc[j] *= inv;
  *(f32x4*)&out[i] = acc;
}

extern "C" void kernel_launch(void* const* d_in, const int* in_sizes, int n_in,
                              void* d_out, int out_size, void* d_ws, size_t ws_size,
                              hipStream_t stream) {
  const float* keys = (const float*)d_in[0];
  const float* values = (const float*)d_in[1];
  const float* importance = (const float*)d_in[2];
  const float* query = (const float*)d_in[3];
  const float* mem = (const float*)d_in[4];
  char* wsb = (char*)d_ws;
  u8* nm8    = (u8*)(wsb + OFF_NM8);
  ush* nmT   = (ush*)(wsb + OFF_NMT);
  ush* mhf   = (ush*)(wsb + OFF_NMT);  // alias (dead after k_usage; nmT written later)
  ush* khf   = (ush*)(wsb + OFF_KHF);
  ush* opart = (ush*)(wsb + OFF_OPART);
  float* zpart = (float*)(wsb + OFF_ZPART);
  float* prio  = (float*)(wsb + OFF_PRIO);
  int* rank    = (int*)(wsb + OFF_RANK);
  float* comb  = (float*)(wsb + OFF_COMB);
  float* zp2   = (float*)(wsb + OFF_ZP2);
  float* invl1 = (float*)(wsb + OFF_COMB + 64);
  float* out = (float*)d_out;

  k_combined<<<Bn, 256, 0, stream>>>(importance, comb);
  k_cvt_f16<<<(ROWS * Dn / 4) / 256, 256, 0, stream>>>(keys, khf);
  k_cvt_f16<<<(CAPn * Dn / 4) / 256, 256, 0, stream>>>(mem, mhf);
  k_rowexp<<<CAPn / 64, 256, 0, stream>>>(mhf, khf, zpart);
  k_invl<<<ROWS / 256, 256, 0, stream>>>(zpart, invl1);
  k_usage<<<dim3(CAPn / 128, Bn), 256, 0, stream>>>(mhf, khf, invl1, comb, prio);
  k_rankinit<<<(Bn * CAPn) / 256, 256, 0, stream>>>(rank);
  k_select<<<Bn, 1024, 0, stream>>>(prio, rank);
  k_newmem8<<<(CAPn * Dn / 4) / 256, 256, 0, stream>>>(mem, values, rank, nm8);
  k_nmT<<<dim3(CAPn / 64, Dn / 64), 256, 0, stream>>>(mem, values, rank, nmT);
  k_attnout<<<dim3(8, ROWS / 128), 512, 0, stream>>>(query, nm8, nmT, opart, zp2);
  k_merge<<<(ROWS * Dn / 4) / 256, 256, 0, stream>>>(opart, zp2, out);
}

// Round 14
// 855.382 us; speedup vs baseline: 1.6447x; 1.0024x over previous
//
#include <hip/hip_runtime.h>
#include <hip/hip_fp8.h>

typedef float f32x4 __attribute__((ext_vector_type(4)));
typedef float f32x16 __attribute__((ext_vector_type(16)));
typedef short s16x8 __attribute__((ext_vector_type(8)));
typedef short s16x4 __attribute__((ext_vector_type(4)));
typedef unsigned short ush;
typedef unsigned char u8;

constexpr int Bn = 4, Tn = 1024, Dn = 512, CAPn = 32768, Kn = 1024;
constexpr int ROWS = Bn * Tn; // 4096
constexpr float SCALE = 0.044194173824159216f; // 1/sqrt(512)
constexpr float SC64 = SCALE / 64.0f;          // nm8 stored as 64*new_mem
constexpr float MOM = 0.99f;
constexpr float RATE_B = 0.0025f; // 0.01 / B

// ---- workspace layout (byte offsets). ws proven >= 102.0e6 B ----
constexpr size_t OFF_NM8   = 0;                      // fp8 [CAP][D] (late) 16.78M
constexpr size_t OFF_NMT   = 33554432;               // bf16 [D][CAP] (alias: mem f16 early)
constexpr size_t OFF_OPART = 67108864;               // bf16 [8][ROWS][D] (late)  -- UNION with:
constexpr size_t OFF_KHF   = 67108864;               //   f16 [ROWS][D] (early)
constexpr size_t OFF_ZPART = 75497472;               //   f32 [512][ROWS] (early)
constexpr size_t OFF_PRIO  = 83886080;               //   f32 [4][CAP] (early)
constexpr size_t OFF_RANK  = 84410368;               //   i32 [4][CAP] (early)
constexpr size_t OFF_COMB  = 84934656;               //   f32 [4] (early; +64: invl1)
constexpr size_t OFF_ZP2   = 100663296;              // f32 [8][ROWS] (late)

#define MFMA(a, b, c) __builtin_amdgcn_mfma_f32_16x16x32_bf16((a), (b), (c), 0, 0, 0)
#define MFMAH(a, b, c) __builtin_amdgcn_mfma_f32_16x16x32_f16((a), (b), (c), 0, 0, 0)
#define MFMA8(a, b, c) __builtin_amdgcn_mfma_f32_16x16x32_fp8_fp8((a), (b), (c), 0, 0, 0)
#define MFMAB32(a, b, c) __builtin_amdgcn_mfma_f32_32x32x16_bf16((a), (b), (c), 0, 0, 0)

__device__ __forceinline__ ush bfrn(float x) {
  unsigned u = __float_as_uint(x);
  return (ush)((u + 0x7FFFu + ((u >> 16) & 1u)) >> 16);
}
__device__ __forceinline__ float bff(ush h) { return __uint_as_float(((unsigned)h) << 16); }
__device__ __forceinline__ ush f16rn(float x) {
  _Float16 h = (_Float16)x;  // v_cvt_f16_f32, RTN
  return *(ush*)&h;
}
__device__ __forceinline__ u8 f8rn(float x) {
  __hip_fp8_e4m3 v(x);
  return (u8)v.__x;
}

__device__ __forceinline__ void gl16(const void* g, void* l) {
  __builtin_amdgcn_global_load_lds(
      (const __attribute__((address_space(1))) void*)(uintptr_t)g,
      (__attribute__((address_space(3))) void*)(uintptr_t)l, 16, 0, 0);
}

// combined[b] = mean(importance[b,:,0])
__global__ void k_combined(const float* __restrict__ imp, float* __restrict__ comb) {
  __shared__ float red[256];
  int b = blockIdx.x;
  float s = 0.f;
  for (int t = threadIdx.x; t < Tn; t += 256) s += imp[(size_t)b * Tn + t];
  red[threadIdx.x] = s;
  __syncthreads();
  for (int off = 128; off > 0; off >>= 1) {
    if (threadIdx.x < (unsigned)off) red[threadIdx.x] += red[threadIdx.x + off];
    __syncthreads();
  }
  if (threadIdx.x == 0) comb[b] = red[0] * (1.0f / Tn);
}

// x -> f16 (RTN). 4 elems/thread.
__global__ void k_cvt_f16(const float* __restrict__ x, ush* __restrict__ o) {
  size_t i = ((size_t)blockIdx.x * 256 + threadIdx.x) * 4;
  f32x4 v = *(const f32x4*)&x[i];
  s16x4 h;
#pragma unroll
  for (int j = 0; j < 4; ++j) h[j] = (short)f16rn(v[j]);
  *(s16x4*)&o[i] = h;
}

// Z partials: zpart[cb][t] = sum over this block's 64 c of exp(A[c,:].B[t,:])
__global__ __launch_bounds__(256, 2) void k_rowexp(const ush* __restrict__ Ahf,
                                                   const ush* __restrict__ Bhf,
                                                   float* __restrict__ zpart) {
  __shared__ ush Bs[64 * 512];
  __shared__ float red[2][64];
  const int tid = threadIdx.x;
  const int lane = tid & 63, wid = tid >> 6;
  const int wc2 = wid >> 1, wt = wid & 1;
  const int l15 = lane & 15, g = lane >> 4;
  const int cb = blockIdx.x;
  const int cBase = cb * 64;

  s16x8 afr[2][16];
#pragma unroll
  for (int mi = 0; mi < 2; ++mi) {
    int c = cBase + wc2 * 32 + mi * 16 + l15;
#pragma unroll
    for (int ks = 0; ks < 16; ++ks)
      afr[mi][ks] = *(const s16x8*)&Ahf[(size_t)c * Dn + ks * 32 + g * 8];
  }

  for (int tt = 0; tt < 64; ++tt) {
    const int tBase = tt * 64;
#pragma unroll
    for (int rr = 0; rr < 16; ++rr) {
      int idx = rr * 256 + tid;
      int row = idx >> 6, ch = idx & 63;
      gl16(&Bhf[(size_t)(tBase + row) * Dn + ((ch ^ (row & 7)) << 3)],
           &Bs[rr * 2048 + wid * 512]);
    }
    __syncthreads();
    f32x4 S[2][2];
#pragma unroll
    for (int mi = 0; mi < 2; ++mi)
#pragma unroll
      for (int ni = 0; ni < 2; ++ni) S[mi][ni] = (f32x4){0.f, 0.f, 0.f, 0.f};
#pragma unroll
    for (int ks = 0; ks < 16; ++ks) {
      s16x8 bfr[2];
#pragma unroll
      for (int ni = 0; ni < 2; ++ni) {
        int trow = wt * 32 + ni * 16 + l15;
        bfr[ni] = *(const s16x8*)&Bs[trow * 512 + (((ks * 4 + g) ^ (trow & 7)) * 8)];
      }
#pragma unroll
      for (int mi = 0; mi < 2; ++mi)
#pragma unroll
        for (int ni = 0; ni < 2; ++ni) S[mi][ni] = MFMAH(afr[mi][ks], bfr[ni], S[mi][ni]);
    }
    float tacc[2] = {0.f, 0.f};
#pragma unroll
    for (int mi = 0; mi < 2; ++mi)
#pragma unroll
      for (int ni = 0; ni < 2; ++ni)
#pragma unroll
        for (int r = 0; r < 4; ++r) tacc[ni] += __expf(S[mi][ni][r]);
#pragma unroll
    for (int ni = 0; ni < 2; ++ni) {
      float v = tacc[ni];
      v += __shfl_xor(v, 16);
      v += __shfl_xor(v, 32);
      tacc[ni] = v;
    }
    if (g == 0) {
      red[wc2][wt * 32 + l15] = tacc[0];
      red[wc2][wt * 32 + 16 + l15] = tacc[1];
    }
    __syncthreads();
    if (tid < 64) zpart[(size_t)cb * ROWS + tBase + tid] = red[0][tid] + red[1][tid];
  }
}

__global__ void k_invl(const float* __restrict__ zpart, float* __restrict__ invl) {
  int t = blockIdx.x * 256 + threadIdx.x;
  float s = 0.f;
  for (int cb = 0; cb < 512; ++cb) s += zpart[(size_t)cb * ROWS + t];
  invl[t] = 1.0f / s;
}

// prio[b,c] = comb[b] + 0.1 * sum_t exp(scores[b,t,c]) * invl1[b,t]
__global__ __launch_bounds__(256, 3) void k_usage(const ush* __restrict__ mhf,
                                                  const ush* __restrict__ khf,
                                                  const float* __restrict__ invl,
                                                  const float* __restrict__ comb,
                                                  float* __restrict__ prio) {
  __shared__ ush Ah[128 * 64], Bh[128 * 64];
  const int tid = threadIdx.x;
  const int lane = tid & 63, w = tid >> 6;
  const int l15 = lane & 15, g = lane >> 4;
  const int cBase = blockIdx.x * 128;
  const int b = blockIdx.y;
  const ush* khb = khf + (size_t)b * Tn * Dn;
  const int r0 = tid >> 3, u0 = tid & 7;
  const int usw = (u0 ^ (r0 & 7)) << 3;

  float uacc[2][4] = {{0.f, 0.f, 0.f, 0.f}, {0.f, 0.f, 0.f, 0.f}};
  for (int tt = 0; tt < 8; ++tt) {
    f32x4 S[2][8];
#pragma unroll
    for (int mi = 0; mi < 2; ++mi)
#pragma unroll
      for (int ni = 0; ni < 8; ++ni) S[mi][ni] = (f32x4){0.f, 0.f, 0.f, 0.f};
    for (int kk = 0; kk < 8; ++kk) {
      __syncthreads();
      {
        size_t a0 = (size_t)(cBase + r0) * Dn + kk * 64 + usw;
        size_t a1 = (size_t)(cBase + r0 + 64) * Dn + kk * 64 + usw;
        gl16(&mhf[a0], &Ah[w * 512]);
        gl16(&mhf[a1], &Ah[4096 + w * 512]);
        size_t b0 = (size_t)(tt * 128 + r0) * Dn + kk * 64 + usw;
        size_t b1 = (size_t)(tt * 128 + r0 + 64) * Dn + kk * 64 + usw;
        gl16(&khb[b0], &Bh[w * 512]);
        gl16(&khb[b1], &Bh[4096 + w * 512]);
      }
      __syncthreads();
#pragma unroll
      for (int ks2 = 0; ks2 < 2; ++ks2) {
        s16x8 ah[2];
#pragma unroll
        for (int mi = 0; mi < 2; ++mi) {
          int crow = w * 32 + mi * 16 + l15;
          ah[mi] = *(const s16x8*)&Ah[crow * 64 + (((ks2 * 4 + g) ^ (crow & 7)) * 8)];
        }
#pragma unroll
        for (int ni = 0; ni < 8; ++ni) {
          int trow = ni * 16 + l15;
          s16x8 bh = *(const s16x8*)&Bh[trow * 64 + (((ks2 * 4 + g) ^ (trow & 7)) * 8)];
#pragma unroll
          for (int mi = 0; mi < 2; ++mi) S[mi][ni] = MFMAH(ah[mi], bh, S[mi][ni]);
        }
      }
    }
#pragma unroll
    for (int ni = 0; ni < 8; ++ni) {
      float il = invl[b * Tn + tt * 128 + ni * 16 + l15];
#pragma unroll
      for (int mi = 0; mi < 2; ++mi)
#pragma unroll
        for (int r = 0; r < 4; ++r) uacc[mi][r] += __expf(S[mi][ni][r]) * il;
    }
  }
#pragma unroll
  for (int mi = 0; mi < 2; ++mi)
#pragma unroll
    for (int r = 0; r < 4; ++r) {
      float v = uacc[mi][r];
      v += __shfl_xor(v, 1);
      v += __shfl_xor(v, 2);
      v += __shfl_xor(v, 4);
      v += __shfl_xor(v, 8);
      if (l15 == 0)
        prio[(size_t)b * CAPn + cBase + w * 32 + mi * 16 + g * 4 + r] =
            comb[b] + 0.1f * v;
    }
}

// rank init: unselected slots get Kn
__global__ void k_rankinit(int* __restrict__ rank) {
  rank[blockIdx.x * 256 + threadIdx.x] = Kn;
}

// Per-batch exact top-K selection + stable rank (jax top_k semantics).
__global__ __launch_bounds__(1024) void k_select(const float* __restrict__ prio,
                                                 int* __restrict__ rank) {
  const int b = blockIdx.x;
  const float* p = prio + (size_t)b * CAPn;
  __shared__ int hist[256];
  __shared__ unsigned long long s_pref;
  __shared__ int s_krem;
  __shared__ int s_cnt;
  __shared__ unsigned long long selk[Kn];
  const int tid = threadIdx.x;
  if (tid == 0) { s_pref = 0ull; s_krem = Kn; s_cnt = 0; }

#define KEYOF(c, kk)                                                         \
  {                                                                          \
    unsigned mb_ = __float_as_uint(p[(c)]);                                  \
    mb_ = (mb_ & 0x80000000u) ? ~mb_ : (mb_ | 0x80000000u);                  \
    (kk) = ((unsigned long long)mb_ << 32) | (unsigned)(0xFFFFFFFFu - (c));  \
  }

  __syncthreads();
  for (int pos = 56; pos >= 0; pos -= 8) {
    if (tid < 256) hist[tid] = 0;
    __syncthreads();
    unsigned long long pref = s_pref;
    unsigned long long maskhi = (pos == 56) ? 0ull : (~0ull << (pos + 8));
    for (int c = tid; c < CAPn; c += 1024) {
      unsigned long long k;
      KEYOF(c, k);
      if ((k & maskhi) == pref) atomicAdd(&hist[(int)((k >> pos) & 255)], 1);
    }
    __syncthreads();
    if (tid == 0) {
      int krem = s_krem;
      int d = 255;
      for (;; --d) {
        int h = hist[d];
        if (krem <= h || d == 0) break;
        krem -= h;
      }
      s_pref = pref | ((unsigned long long)d << pos);
      s_krem = krem;
    }
    __syncthreads();
  }
  unsigned long long T = s_pref;  // exact Kn-th largest key
  for (int c = tid; c < CAPn; c += 1024) {
    unsigned long long k;
    KEYOF(c, k);
    if (k >= T) {
      int idx = atomicAdd(&s_cnt, 1);
      selk[idx] = k;
    }
  }
  __syncthreads();
  unsigned long long mine = selk[tid];
  int r = 0;
  for (int j = 0; j < Kn; ++j) r += (selk[j] > mine) ? 1 : 0;
  int c = (int)(0xFFFFFFFFu - (unsigned)(mine & 0xFFFFFFFFull));
  rank[(size_t)b * CAPn + c] = r;
#undef KEYOF
}

// nm8 (fp8 e4m3) = 64 * (0.99*mem + 0.0025*sum_b selected values)   [r10/r12-proven]
__global__ void k_newmem8(const float* __restrict__ mem, const float* __restrict__ values,
                          const int* __restrict__ rank, u8* __restrict__ nm8) {
  int gid = blockIdx.x * 256 + threadIdx.x;
  int c = gid >> 7;
  int q = (gid & 127) << 2;
  f32x4 m = *(const f32x4*)&mem[(size_t)c * Dn + q];
  f32x4 acc = {0.f, 0.f, 0.f, 0.f};
#pragma unroll
  for (int b = 0; b < Bn; ++b) {
    int r = rank[(size_t)b * CAPn + c];
    if (r < Kn) acc += *(const f32x4*)&values[((size_t)b * Tn + r) * Dn + q];
  }
  f32x4 res = (m * MOM + acc * RATE_B) * 64.0f;
  union { u8 b[4]; unsigned w; } out;
#pragma unroll
  for (int j = 0; j < 4; ++j) out.b[j] = f8rn(res[j]);
  *(unsigned*)&nm8[(size_t)c * Dn + q] = out.w;
}

// nmT[d][c] = new_mem[c][d] (bf16), recomputed from mem/values/rank. [r10/r12-proven]
__global__ __launch_bounds__(256) void k_nmT(const float* __restrict__ mem,
                                             const float* __restrict__ values,
                                             const int* __restrict__ rank,
                                             ush* __restrict__ nmT) {
  __shared__ ush tile[64][65];
  int cBase = blockIdx.x * 64, dBase = blockIdx.y * 64;
  int tid = threadIdx.x;
  int c = tid >> 2, dq = (tid & 3) * 16;
  int rr[4];
#pragma unroll
  for (int b = 0; b < Bn; ++b) rr[b] = rank[(size_t)b * CAPn + cBase + c];
#pragma unroll
  for (int j = 0; j < 4; ++j) {
    f32x4 m = *(const f32x4*)&mem[(size_t)(cBase + c) * Dn + dBase + dq + j * 4];
    f32x4 a = {0.f, 0.f, 0.f, 0.f};
#pragma unroll
    for (int b = 0; b < Bn; ++b)
      if (rr[b] < Kn)
        a += *(const f32x4*)&values[((size_t)b * Tn + rr[b]) * Dn + dBase + dq + j * 4];
    f32x4 res = m * MOM + a * RATE_B;
#pragma unroll
    for (int jj = 0; jj < 4; ++jj) tile[c][dq + j * 4 + jj] = bfrn(res[jj]);
  }
  __syncthreads();
  int drow = tid >> 2, cq = (tid & 3) * 16;
#pragma unroll
  for (int k = 0; k < 2; ++k) {
    s16x8 v;
#pragma unroll
    for (int j = 0; j < 8; ++j) v[j] = (short)tile[cq + k * 8 + j][drow];
    *(s16x8*)&nmT[(size_t)(dBase + drow) * CAPn + cBase + cq + k * 8] = v;
  }
}

// Fused attn: r12 pipeline/staging, QK fp8 16x16x32, PV 32x32x16 bf16.
// FIX vs r13: pb logical unit now includes the (u&1)*8 c-half offset.
// 13 phases/ct, counted vmcnt(2), WAR-safe post-BAR staging.
// LDS bytes: Ms8[3][128c][128k-fp8] 48KB @0; Mt[3][128d][64c] bf16 48KB @49152;
//            Ps[128q][128c] bf16 32KB @98304 (epilogue: [32q][512d]).
#define WAITV2 asm volatile("s_waitcnt vmcnt(2)" ::: "memory")
#define WAITL0 asm volatile("s_waitcnt lgkmcnt(0)" ::: "memory")
#define BAR __builtin_amdgcn_s_barrier()
__global__ __launch_bounds__(512, 1) void k_attnout(
    const float* __restrict__ query, const u8* __restrict__ nm8,
    const ush* __restrict__ nmT, ush* __restrict__ opart,
    float* __restrict__ zp2) {
  __shared__ __align__(16) u8 L[131072];
  __shared__ float zred[128];
  __shared__ float zacc[128];
  constexpr int LMS = 0, LMT = 49152, LPS = 98304;  // byte offsets
  const int tid = threadIdx.x;
  const int lane = tid & 63, w = tid >> 6;
  const int l15 = lane & 15, g = lane >> 4;
  const int l31 = lane & 31, h = lane >> 5;
  const int dt = w & 3, qg = w >> 2;  // PV decomposition
  const int cy = blockIdx.x;
  const int qBase = blockIdx.y * 128;
  const int q = w * 16 + l15;  // QK/P-phase q ownership (16x16 S layout)
  const int r0 = tid >> 3, u0 = tid & 7;
  const int usw = (u0 ^ (r0 & 7)) << 3;   // ush units (nmT staging, 128B rows)
  const int usw8 = (u0 ^ (r0 & 7)) << 4;  // bytes (nm8 staging, 128B rows)

  auto stage_ms = [&](int buf, int cb_, int kk) {
    const u8* src = nm8 + (size_t)cb_ * Dn + kk * 128;
    gl16(&src[(size_t)r0 * Dn + usw8], &L[LMS + buf * 16384 + w * 1024]);
    gl16(&src[(size_t)(r0 + 64) * Dn + usw8], &L[LMS + buf * 16384 + 8192 + w * 1024]);
  };
  auto stage_mt = [&](int buf, int cb_, int u) {
    const ush* src = nmT + (size_t)((u >> 1) * 128) * CAPn + cb_ + (u & 1) * 64;
    gl16(&src[(size_t)r0 * CAPn + usw], &L[LMT + buf * 16384 + w * 1024]);
    gl16(&src[(size_t)(r0 + 64) * CAPn + usw], &L[LMT + buf * 16384 + 8192 + w * 1024]);
  };

  // Q fp8 fragments in registers: row qBase+q, K=512 as 16 chunks of 32.
  long qfr8[16];
  {
    const float* qsrc = query + (size_t)(qBase + q) * Dn;
#pragma unroll
    for (int ks = 0; ks < 16; ++ks) {
      f32x4 a = *(const f32x4*)&qsrc[ks * 32 + g * 8];
      f32x4 b = *(const f32x4*)&qsrc[ks * 32 + g * 8 + 4];
      union { u8 c[8]; long l; } u;
#pragma unroll
      for (int j = 0; j < 4; ++j) {
        u.c[j] = f8rn(a[j]);
        u.c[4 + j] = f8rn(b[j]);
      }
      qfr8[ks] = u.l;
    }
  }

  // PV accumulator: O[db*2+tqi] = 32x32 tile, d = db*128 + dt*32 + row32,
  // q = qg*64 + tqi*32 + col32 (C layout: col=lane&31, row=(reg&3)+8*(reg>>2)+4*h)
  f32x16 O[8];
#pragma unroll
  for (int i = 0; i < 8; ++i) O[i] = (f32x16)(0.f);
  if (tid < 128) zacc[tid] = 0.f;

  stage_ms(0, cy * 4096, 0);
  stage_ms(1, cy * 4096, 1);

  for (int ct = 0; ct < 32; ++ct) {
    const int cBase = cy * 4096 + ct * 128;
    const int cNext = cy * 4096 + ((ct + 1) & 31) * 128;

    // ---- QK phases kk=0..3 (K-chunks of 128 fp8): consume Ms[kk%3] ----
    f32x4 S[8];
#pragma unroll
    for (int i = 0; i < 8; ++i) S[i] = (f32x4){0.f, 0.f, 0.f, 0.f};
#pragma unroll
    for (int kk = 0; kk < 4; ++kk) {
      WAITV2;
      WAITL0;
      BAR;
      if (kk < 2) stage_ms((kk + 2) % 3, cBase, kk + 2);
      else if (kk == 2) stage_mt(0, cBase, 0);
      else stage_mt(1, cBase, 1);
      __builtin_amdgcn_s_setprio(1);
#pragma unroll
      for (int ks = 0; ks < 4; ++ks) {
#pragma unroll
        for (int mi = 0; mi < 8; ++mi) {
          int row = mi * 16 + l15;
          long a = *(const long*)&L[LMS + (kk % 3) * 16384 + row * 128 +
                                    (((ks * 2 + (g >> 1)) ^ (row & 7)) << 4) +
                                    (g & 1) * 8];
          S[mi] = MFMA8(a, qfr8[kk * 4 + ks], S[mi]);
        }
      }
      __builtin_amdgcn_s_setprio(0);
    }

    // ---- P phase: exp(S*SC64) -> Ps (unnormalized); z partial. No stage. ----
    float zl = 0.f;
#pragma unroll
    for (int mi = 0; mi < 8; ++mi) {
      s16x4 p;
#pragma unroll
      for (int r = 0; r < 4; ++r) {
        float e = __expf(S[mi][r] * SC64);
        zl += e;
        p[r] = (short)bfrn(e);
      }
      int u16 = (mi * 2 + (g >> 1)) ^ l15;
      *(s16x4*)&L[LPS + q * 256 + u16 * 16 + (g & 1) * 8] = p;
    }
    zl += __shfl_xor(zl, 16);
    zl += __shfl_xor(zl, 32);
    if (g == 0) zred[q] = zl;
    WAITL0;
    BAR;
    if (tid < 128) zacc[tid] += zred[tid];

    // ---- PV phases u=0..7: 32x32x16 bf16; wave = (dt, qg x 2 q-tiles) ----
#pragma unroll
    for (int u = 0; u < 8; ++u) {
      WAITV2;
      WAITL0;
      BAR;
      if (u < 6) stage_mt((u + 2) % 3, cBase, u + 2);
      else if (u == 6) stage_ms(0, cNext, 0);
      else stage_ms(1, cNext, 1);
      __builtin_amdgcn_s_setprio(1);
#pragma unroll
      for (int kc = 0; kc < 4; ++kc) {
        int d = dt * 32 + l31;
        s16x8 am = *(const s16x8*)&L[LMT + (u % 3) * 16384 + d * 128 +
                                     (((kc * 2 + h) ^ (d & 7)) << 4)];
#pragma unroll
        for (int tqi = 0; tqi < 2; ++tqi) {
          int qq = qg * 64 + tqi * 32 + l31;
          s16x8 pb = *(const s16x8*)&L[LPS + qq * 256 +
                                       ((((u & 1) * 8 + kc * 2 + h) ^ (qq & 15)) << 4)];
          O[(u >> 1) * 2 + tqi] = MFMAB32(am, pb, O[(u >> 1) * 2 + tqi]);
        }
      }
      __builtin_amdgcn_s_setprio(0);
    }
  }

  // ---- epilogue: drain, z store, O via 4-pass [32q][512d] LDS transpose ----
  __syncthreads();
  if (tid < 128) zp2[(size_t)cy * ROWS + qBase + tid] = zacc[tid];
#pragma unroll
  for (int p = 0; p < 4; ++p) {
    __syncthreads();
    if (qg == (p >> 1)) {
      const int tqi = p & 1;
#pragma unroll
      for (int db = 0; db < 4; ++db)
#pragma unroll
        for (int r2 = 0; r2 < 4; ++r2) {
          s16x4 ov;
#pragma unroll
          for (int j = 0; j < 4; ++j) ov[j] = (short)bfrn(O[db * 2 + tqi][r2 * 4 + j]);
          int u8i = db * 32 + dt * 8 + r2 * 2 + h;  // d>>2 unit
          int u8s = u8i ^ ((l31 & 15) << 1);
          *(s16x4*)&L[LPS + l31 * 1024 + u8s * 8] = ov;
        }
    }
    __syncthreads();
#pragma unroll
    for (int i = 0; i < 4; ++i) {
      int slot = i * 512 + tid;
      int ql = slot >> 6, u16 = slot & 63;
      s16x8 v = *(const s16x8*)&L[LPS + ql * 1024 + ((u16 ^ (ql & 15)) << 4)];
      *(s16x8*)&opart[((size_t)cy * ROWS + qBase + p * 32 + ql) * Dn + u16 * 8] = v;
    }
  }
}

// out = (sum_cy opart[cy]) / (sum_cy zp2[cy]) per row
__global__ void k_merge(const ush* __restrict__ opart, const float* __restrict__ zp2,
                        float* __restrict__ out) {
  size_t i = ((size_t)blockIdx.x * 256 + threadIdx.x) * 4;
  int row = (int)(i >> 9);
  float z = 0.f;
#pragma unroll
  for (int cyy = 0; cyy < 8; ++cyy) z += zp2[(size_t)cyy * ROWS + row];
  float inv = 1.0f / z;
  f32x4 acc = {0.f, 0.f, 0.f, 0.f};
#pragma unroll
  for (int cyy = 0; cyy < 8; ++cyy) {
    s16x4 a = *(const s16x4*)&opart[(size_t)cyy * ROWS * Dn + i];
#pragma unroll
    for (int j = 0; j < 4; ++j) acc[j] += bff((ush)a[j]);
  }
#pragma unroll
  for (int j = 0; j < 4; ++j) acc[j] *= inv;
  *(f32x4*)&out[i] = acc;
}

extern "C" void kernel_launch(void* const* d_in, const int* in_sizes, int n_in,
                              void* d_out, int out_size, void* d_ws, size_t ws_size,
                              hipStream_t stream) {
  const float* keys = (const float*)d_in[0];
  const float* values = (const float*)d_in[1];
  const float* importance = (const float*)d_in[2];
  const float* query = (const float*)d_in[3];
  const float* mem = (const float*)d_in[4];
  char* wsb = (char*)d_ws;
  u8* nm8    = (u8*)(wsb + OFF_NM8);
  ush* nmT   = (ush*)(wsb + OFF_NMT);
  ush* mhf   = (ush*)(wsb + OFF_NMT);  // alias (dead after k_usage; nmT written later)
  ush* khf   = (ush*)(wsb + OFF_KHF);
  ush* opart = (ush*)(wsb + OFF_OPART);
  float* zpart = (float*)(wsb + OFF_ZPART);
  float* prio  = (float*)(wsb + OFF_PRIO);
  int* rank    = (int*)(wsb + OFF_RANK);
  float* comb  = (float*)(wsb + OFF_COMB);
  float* zp2   = (float*)(wsb + OFF_ZP2);
  float* invl1 = (float*)(wsb + OFF_COMB + 64);
  float* out = (float*)d_out;

  k_combined<<<Bn, 256, 0, stream>>>(importance, comb);
  k_cvt_f16<<<(ROWS * Dn / 4) / 256, 256, 0, stream>>>(keys, khf);
  k_cvt_f16<<<(CAPn * Dn / 4) / 256, 256, 0, stream>>>(mem, mhf);
  k_rowexp<<<CAPn / 64, 256, 0, stream>>>(mhf, khf, zpart);
  k_invl<<<ROWS / 256, 256, 0, stream>>>(zpart, invl1);
  k_usage<<<dim3(CAPn / 128, Bn), 256, 0, stream>>>(mhf, khf, invl1, comb, prio);
  k_rankinit<<<(Bn * CAPn) / 256, 256, 0, stream>>>(rank);
  k_select<<<Bn, 1024, 0, stream>>>(prio, rank);
  k_newmem8<<<(CAPn * Dn / 4) / 256, 256, 0, stream>>>(mem, values, rank, nm8);
  k_nmT<<<dim3(CAPn / 64, Dn / 64), 256, 0, stream>>>(mem, values, rank, nmT);
  k_attnout<<<dim3(8, ROWS / 128), 512, 0, stream>>>(query, nm8, nmT, opart, zp2);
  k_merge<<<(ROWS * Dn / 4) / 256, 256, 0, stream>>>(opart, zp2, out);
}

// Round 15
// 789.109 us; speedup vs baseline: 1.7828x; 1.0840x over previous
//
#include <hip/hip_runtime.h>
#include <hip/hip_fp8.h>

typedef float f32x4 __attribute__((ext_vector_type(4)));
typedef float f32x16 __attribute__((ext_vector_type(16)));
typedef short s16x8 __attribute__((ext_vector_type(8)));
typedef short s16x4 __attribute__((ext_vector_type(4)));
typedef unsigned short ush;
typedef unsigned char u8;

constexpr int Bn = 4, Tn = 1024, Dn = 512, CAPn = 32768, Kn = 1024;
constexpr int ROWS = Bn * Tn; // 4096
constexpr float SCALE = 0.044194173824159216f; // 1/sqrt(512)
constexpr float SC64 = SCALE / 64.0f;          // nm8 stored as 64*new_mem
constexpr float MOM = 0.99f;
constexpr float RATE_B = 0.0025f; // 0.01 / B

// ---- workspace layout (byte offsets). ws proven >= 102.0e6 B ----
constexpr size_t OFF_NM8   = 0;                      // fp8 [CAP][D] (late) 16.78M
constexpr size_t OFF_NMT   = 33554432;               // bf16 [D][CAP] (alias: mem f16 early)
constexpr size_t OFF_OPART = 67108864;               // bf16 [8][ROWS][D] (late)  -- UNION with:
constexpr size_t OFF_KHF   = 67108864;               //   f16 [ROWS][D] (early)
constexpr size_t OFF_ZPART = 75497472;               //   f32 [512][ROWS] (early)
constexpr size_t OFF_PRIO  = 83886080;               //   f32 [4][CAP] (early)
constexpr size_t OFF_RANK  = 84410368;               //   i32 [4][CAP] (early)
constexpr size_t OFF_COMB  = 84934656;               //   f32 [4] (early; +64: invl1)
constexpr size_t OFF_ZP2   = 100663296;              // f32 [8][ROWS] (late)

#define MFMA(a, b, c) __builtin_amdgcn_mfma_f32_16x16x32_bf16((a), (b), (c), 0, 0, 0)
#define MFMAH(a, b, c) __builtin_amdgcn_mfma_f32_16x16x32_f16((a), (b), (c), 0, 0, 0)
#define MFMA8(a, b, c) __builtin_amdgcn_mfma_f32_16x16x32_fp8_fp8((a), (b), (c), 0, 0, 0)
#define MFMAB32(a, b, c) __builtin_amdgcn_mfma_f32_32x32x16_bf16((a), (b), (c), 0, 0, 0)

__device__ __forceinline__ ush bfrn(float x) {
  unsigned u = __float_as_uint(x);
  return (ush)((u + 0x7FFFu + ((u >> 16) & 1u)) >> 16);
}
__device__ __forceinline__ float bff(ush h) { return __uint_as_float(((unsigned)h) << 16); }
__device__ __forceinline__ ush f16rn(float x) {
  _Float16 h = (_Float16)x;  // v_cvt_f16_f32, RTN
  return *(ush*)&h;
}
__device__ __forceinline__ u8 f8rn(float x) {
  __hip_fp8_e4m3 v(x);
  return (u8)v.__x;
}

__device__ __forceinline__ void gl16(const void* g, void* l) {
  __builtin_amdgcn_global_load_lds(
      (const __attribute__((address_space(1))) void*)(uintptr_t)g,
      (__attribute__((address_space(3))) void*)(uintptr_t)l, 16, 0, 0);
}

// combined[b] = mean(importance[b,:,0])
__global__ void k_combined(const float* __restrict__ imp, float* __restrict__ comb) {
  __shared__ float red[256];
  int b = blockIdx.x;
  float s = 0.f;
  for (int t = threadIdx.x; t < Tn; t += 256) s += imp[(size_t)b * Tn + t];
  red[threadIdx.x] = s;
  __syncthreads();
  for (int off = 128; off > 0; off >>= 1) {
    if (threadIdx.x < (unsigned)off) red[threadIdx.x] += red[threadIdx.x + off];
    __syncthreads();
  }
  if (threadIdx.x == 0) comb[b] = red[0] * (1.0f / Tn);
}

// mem -> mhf (blocks 0..16383), keys -> khf (blocks 16384..18431). f16 RTN, 4/thread.
__global__ void k_cvt_all(const float* __restrict__ mem, const float* __restrict__ keys,
                          ush* __restrict__ mhf, ush* __restrict__ khf) {
  int bid = blockIdx.x;
  const float* src;
  ush* dst;
  size_t i;
  if (bid < 16384) {
    src = mem;
    dst = mhf;
    i = ((size_t)bid * 256 + threadIdx.x) * 4;
  } else {
    src = keys;
    dst = khf;
    i = ((size_t)(bid - 16384) * 256 + threadIdx.x) * 4;
  }
  f32x4 v = *(const f32x4*)&src[i];
  s16x4 h;
#pragma unroll
  for (int j = 0; j < 4; ++j) h[j] = (short)f16rn(v[j]);
  *(s16x4*)&dst[i] = h;
}

// Z partials: zpart[cb][t] = sum over this block's 64 c of exp(A[c,:].B[t,:])
__global__ __launch_bounds__(256, 2) void k_rowexp(const ush* __restrict__ Ahf,
                                                   const ush* __restrict__ Bhf,
                                                   float* __restrict__ zpart) {
  __shared__ ush Bs[64 * 512];
  __shared__ float red[2][64];
  const int tid = threadIdx.x;
  const int lane = tid & 63, wid = tid >> 6;
  const int wc2 = wid >> 1, wt = wid & 1;
  const int l15 = lane & 15, g = lane >> 4;
  const int cb = blockIdx.x;
  const int cBase = cb * 64;

  s16x8 afr[2][16];
#pragma unroll
  for (int mi = 0; mi < 2; ++mi) {
    int c = cBase + wc2 * 32 + mi * 16 + l15;
#pragma unroll
    for (int ks = 0; ks < 16; ++ks)
      afr[mi][ks] = *(const s16x8*)&Ahf[(size_t)c * Dn + ks * 32 + g * 8];
  }

  for (int tt = 0; tt < 64; ++tt) {
    const int tBase = tt * 64;
#pragma unroll
    for (int rr = 0; rr < 16; ++rr) {
      int idx = rr * 256 + tid;
      int row = idx >> 6, ch = idx & 63;
      gl16(&Bhf[(size_t)(tBase + row) * Dn + ((ch ^ (row & 7)) << 3)],
           &Bs[rr * 2048 + wid * 512]);
    }
    __syncthreads();
    f32x4 S[2][2];
#pragma unroll
    for (int mi = 0; mi < 2; ++mi)
#pragma unroll
      for (int ni = 0; ni < 2; ++ni) S[mi][ni] = (f32x4){0.f, 0.f, 0.f, 0.f};
#pragma unroll
    for (int ks = 0; ks < 16; ++ks) {
      s16x8 bfr[2];
#pragma unroll
      for (int ni = 0; ni < 2; ++ni) {
        int trow = wt * 32 + ni * 16 + l15;
        bfr[ni] = *(const s16x8*)&Bs[trow * 512 + (((ks * 4 + g) ^ (trow & 7)) * 8)];
      }
#pragma unroll
      for (int mi = 0; mi < 2; ++mi)
#pragma unroll
        for (int ni = 0; ni < 2; ++ni) S[mi][ni] = MFMAH(afr[mi][ks], bfr[ni], S[mi][ni]);
    }
    float tacc[2] = {0.f, 0.f};
#pragma unroll
    for (int mi = 0; mi < 2; ++mi)
#pragma unroll
      for (int ni = 0; ni < 2; ++ni)
#pragma unroll
        for (int r = 0; r < 4; ++r) tacc[ni] += __expf(S[mi][ni][r]);
#pragma unroll
    for (int ni = 0; ni < 2; ++ni) {
      float v = tacc[ni];
      v += __shfl_xor(v, 16);
      v += __shfl_xor(v, 32);
      tacc[ni] = v;
    }
    if (g == 0) {
      red[wc2][wt * 32 + l15] = tacc[0];
      red[wc2][wt * 32 + 16 + l15] = tacc[1];
    }
    __syncthreads();
    if (tid < 64) zpart[(size_t)cb * ROWS + tBase + tid] = red[0][tid] + red[1][tid];
  }
}

__global__ void k_invl(const float* __restrict__ zpart, float* __restrict__ invl) {
  int t = blockIdx.x * 256 + threadIdx.x;
  float s = 0.f;
  for (int cb = 0; cb < 512; ++cb) s += zpart[(size_t)cb * ROWS + t];
  invl[t] = 1.0f / s;
}

#define WAITV0 asm volatile("s_waitcnt vmcnt(0)" ::: "memory")
#define WAITV2 asm volatile("s_waitcnt vmcnt(2)" ::: "memory")
#define WAITL0 asm volatile("s_waitcnt lgkmcnt(0)" ::: "memory")
#define BAR __builtin_amdgcn_s_barrier()

// prio[b,c] = comb[b] + 0.1 * sum_t exp(scores[b,t,c]) * invl1[b,t]
// A (mem f16) hoisted to registers (afr[2][16], wave owns 32 c full-K);
// B double-buffered, stage issued post-BAR (r11-proven WAR-safe pipeline).
// MFMA order identical to r14 -> prio bitwise identical.
__global__ __launch_bounds__(256, 2) void k_usage(const ush* __restrict__ mhf,
                                                  const ush* __restrict__ khf,
                                                  const float* __restrict__ invl,
                                                  const float* __restrict__ comb,
                                                  float* __restrict__ prio) {
  __shared__ ush Bh[2][128 * 64];
  const int tid = threadIdx.x;
  const int lane = tid & 63, w = tid >> 6;
  const int l15 = lane & 15, g = lane >> 4;
  const int cBase = blockIdx.x * 128;
  const int b = blockIdx.y;
  const ush* khb = khf + (size_t)b * Tn * Dn;
  const int r0 = tid >> 3, u0 = tid & 7;
  const int usw = (u0 ^ (r0 & 7)) << 3;

  s16x8 afr[2][16];
#pragma unroll
  for (int mi = 0; mi < 2; ++mi) {
    int c = cBase + w * 32 + mi * 16 + l15;
#pragma unroll
    for (int ks = 0; ks < 16; ++ks)
      afr[mi][ks] = *(const s16x8*)&mhf[(size_t)c * Dn + ks * 32 + g * 8];
  }

  auto stageB = [&](int p) {  // p = tt*8 + kk
    int tt = p >> 3, kk = p & 7;
    size_t b0 = (size_t)(tt * 128 + r0) * Dn + kk * 64 + usw;
    size_t b1 = (size_t)(tt * 128 + r0 + 64) * Dn + kk * 64 + usw;
    gl16(&khb[b0], &Bh[p & 1][w * 512]);
    gl16(&khb[b1], &Bh[p & 1][4096 + w * 512]);
  };

  float uacc[2][4] = {{0.f, 0.f, 0.f, 0.f}, {0.f, 0.f, 0.f, 0.f}};
  stageB(0);
  for (int tt = 0; tt < 8; ++tt) {
    f32x4 S[2][8];
#pragma unroll
    for (int mi = 0; mi < 2; ++mi)
#pragma unroll
      for (int ni = 0; ni < 8; ++ni) S[mi][ni] = (f32x4){0.f, 0.f, 0.f, 0.f};
#pragma unroll
    for (int kk = 0; kk < 8; ++kk) {
      const int p = tt * 8 + kk;
      WAITV0;
      WAITL0;
      BAR;
      if (p < 63) stageB(p + 1);
      __builtin_amdgcn_s_setprio(1);
#pragma unroll
      for (int ks2 = 0; ks2 < 2; ++ks2) {
#pragma unroll
        for (int ni = 0; ni < 8; ++ni) {
          int trow = ni * 16 + l15;
          s16x8 bh =
              *(const s16x8*)&Bh[p & 1][trow * 64 + (((ks2 * 4 + g) ^ (trow & 7)) * 8)];
#pragma unroll
          for (int mi = 0; mi < 2; ++mi)
            S[mi][ni] = MFMAH(afr[mi][kk * 2 + ks2], bh, S[mi][ni]);
        }
      }
      __builtin_amdgcn_s_setprio(0);
    }
#pragma unroll
    for (int ni = 0; ni < 8; ++ni) {
      float il = invl[b * Tn + tt * 128 + ni * 16 + l15];
#pragma unroll
      for (int mi = 0; mi < 2; ++mi)
#pragma unroll
        for (int r = 0; r < 4; ++r) uacc[mi][r] += __expf(S[mi][ni][r]) * il;
    }
  }
#pragma unroll
  for (int mi = 0; mi < 2; ++mi)
#pragma unroll
    for (int r = 0; r < 4; ++r) {
      float v = uacc[mi][r];
      v += __shfl_xor(v, 1);
      v += __shfl_xor(v, 2);
      v += __shfl_xor(v, 4);
      v += __shfl_xor(v, 8);
      if (l15 == 0)
        prio[(size_t)b * CAPn + cBase + w * 32 + mi * 16 + g * 4 + r] =
            comb[b] + 0.1f * v;
    }
}

// rank init: unselected slots get Kn
__global__ void k_rankinit(int* __restrict__ rank) {
  rank[blockIdx.x * 256 + threadIdx.x] = Kn;
}

// Per-batch exact top-K selection + stable rank (jax top_k semantics).
__global__ __launch_bounds__(1024) void k_select(const float* __restrict__ prio,
                                                 int* __restrict__ rank) {
  const int b = blockIdx.x;
  const float* p = prio + (size_t)b * CAPn;
  __shared__ int hist[256];
  __shared__ unsigned long long s_pref;
  __shared__ int s_krem;
  __shared__ int s_cnt;
  __shared__ unsigned long long selk[Kn];
  const int tid = threadIdx.x;
  if (tid == 0) { s_pref = 0ull; s_krem = Kn; s_cnt = 0; }

#define KEYOF(c, kk)                                                         \
  {                                                                          \
    unsigned mb_ = __float_as_uint(p[(c)]);                                  \
    mb_ = (mb_ & 0x80000000u) ? ~mb_ : (mb_ | 0x80000000u);                  \
    (kk) = ((unsigned long long)mb_ << 32) | (unsigned)(0xFFFFFFFFu - (c));  \
  }

  __syncthreads();
  for (int pos = 56; pos >= 0; pos -= 8) {
    if (tid < 256) hist[tid] = 0;
    __syncthreads();
    unsigned long long pref = s_pref;
    unsigned long long maskhi = (pos == 56) ? 0ull : (~0ull << (pos + 8));
    for (int c = tid; c < CAPn; c += 1024) {
      unsigned long long k;
      KEYOF(c, k);
      if ((k & maskhi) == pref) atomicAdd(&hist[(int)((k >> pos) & 255)], 1);
    }
    __syncthreads();
    if (tid == 0) {
      int krem = s_krem;
      int d = 255;
      for (;; --d) {
        int h = hist[d];
        if (krem <= h || d == 0) break;
        krem -= h;
      }
      s_pref = pref | ((unsigned long long)d << pos);
      s_krem = krem;
    }
    __syncthreads();
  }
  unsigned long long T = s_pref;  // exact Kn-th largest key
  for (int c = tid; c < CAPn; c += 1024) {
    unsigned long long k;
    KEYOF(c, k);
    if (k >= T) {
      int idx = atomicAdd(&s_cnt, 1);
      selk[idx] = k;
    }
  }
  __syncthreads();
  unsigned long long mine = selk[tid];
  int r = 0;
  for (int j = 0; j < Kn; ++j) r += (selk[j] > mine) ? 1 : 0;
  int c = (int)(0xFFFFFFFFu - (unsigned)(mine & 0xFFFFFFFFull));
  rank[(size_t)b * CAPn + c] = r;
#undef KEYOF
}

// nm8 (fp8 e4m3) = 64 * (0.99*mem + 0.0025*sum_b selected values)
__global__ void k_newmem8(const float* __restrict__ mem, const float* __restrict__ values,
                          const int* __restrict__ rank, u8* __restrict__ nm8) {
  int gid = blockIdx.x * 256 + threadIdx.x;
  int c = gid >> 7;
  int q = (gid & 127) << 2;
  f32x4 m = *(const f32x4*)&mem[(size_t)c * Dn + q];
  f32x4 acc = {0.f, 0.f, 0.f, 0.f};
#pragma unroll
  for (int b = 0; b < Bn; ++b) {
    int r = rank[(size_t)b * CAPn + c];
    if (r < Kn) acc += *(const f32x4*)&values[((size_t)b * Tn + r) * Dn + q];
  }
  f32x4 res = (m * MOM + acc * RATE_B) * 64.0f;
  union { u8 b[4]; unsigned w; } out;
#pragma unroll
  for (int j = 0; j < 4; ++j) out.b[j] = f8rn(res[j]);
  *(unsigned*)&nm8[(size_t)c * Dn + q] = out.w;
}

// nmT[d][c] = new_mem[c][d] (bf16), recomputed from mem/values/rank.
__global__ __launch_bounds__(256) void k_nmT(const float* __restrict__ mem,
                                             const float* __restrict__ values,
                                             const int* __restrict__ rank,
                                             ush* __restrict__ nmT) {
  __shared__ ush tile[64][65];
  int cBase = blockIdx.x * 64, dBase = blockIdx.y * 64;
  int tid = threadIdx.x;
  int c = tid >> 2, dq = (tid & 3) * 16;
  int rr[4];
#pragma unroll
  for (int b = 0; b < Bn; ++b) rr[b] = rank[(size_t)b * CAPn + cBase + c];
#pragma unroll
  for (int j = 0; j < 4; ++j) {
    f32x4 m = *(const f32x4*)&mem[(size_t)(cBase + c) * Dn + dBase + dq + j * 4];
    f32x4 a = {0.f, 0.f, 0.f, 0.f};
#pragma unroll
    for (int b = 0; b < Bn; ++b)
      if (rr[b] < Kn)
        a += *(const f32x4*)&values[((size_t)b * Tn + rr[b]) * Dn + dBase + dq + j * 4];
    f32x4 res = m * MOM + a * RATE_B;
#pragma unroll
    for (int jj = 0; jj < 4; ++jj) tile[c][dq + j * 4 + jj] = bfrn(res[jj]);
  }
  __syncthreads();
  int drow = tid >> 2, cq = (tid & 3) * 16;
#pragma unroll
  for (int k = 0; k < 2; ++k) {
    s16x8 v;
#pragma unroll
    for (int j = 0; j < 8; ++j) v[j] = (short)tile[cq + k * 8 + j][drow];
    *(s16x8*)&nmT[(size_t)(dBase + drow) * CAPn + cBase + cq + k * 8] = v;
  }
}

// Fused attn (r14, proven 300us): QK fp8 16x16x32, PV 32x32x16 bf16,
// counted vmcnt(2), WAR-safe post-BAR staging.
__global__ __launch_bounds__(512, 1) void k_attnout(
    const float* __restrict__ query, const u8* __restrict__ nm8,
    const ush* __restrict__ nmT, ush* __restrict__ opart,
    float* __restrict__ zp2) {
  __shared__ __align__(16) u8 L[131072];
  __shared__ float zred[128];
  __shared__ float zacc[128];
  constexpr int LMS = 0, LMT = 49152, LPS = 98304;  // byte offsets
  const int tid = threadIdx.x;
  const int lane = tid & 63, w = tid >> 6;
  const int l15 = lane & 15, g = lane >> 4;
  const int l31 = lane & 31, h = lane >> 5;
  const int dt = w & 3, qg = w >> 2;  // PV decomposition
  const int cy = blockIdx.x;
  const int qBase = blockIdx.y * 128;
  const int q = w * 16 + l15;  // QK/P-phase q ownership (16x16 S layout)
  const int r0 = tid >> 3, u0 = tid & 7;
  const int usw = (u0 ^ (r0 & 7)) << 3;   // ush units (nmT staging, 128B rows)
  const int usw8 = (u0 ^ (r0 & 7)) << 4;  // bytes (nm8 staging, 128B rows)

  auto stage_ms = [&](int buf, int cb_, int kk) {
    const u8* src = nm8 + (size_t)cb_ * Dn + kk * 128;
    gl16(&src[(size_t)r0 * Dn + usw8], &L[LMS + buf * 16384 + w * 1024]);
    gl16(&src[(size_t)(r0 + 64) * Dn + usw8], &L[LMS + buf * 16384 + 8192 + w * 1024]);
  };
  auto stage_mt = [&](int buf, int cb_, int u) {
    const ush* src = nmT + (size_t)((u >> 1) * 128) * CAPn + cb_ + (u & 1) * 64;
    gl16(&src[(size_t)r0 * CAPn + usw], &L[LMT + buf * 16384 + w * 1024]);
    gl16(&src[(size_t)(r0 + 64) * CAPn + usw], &L[LMT + buf * 16384 + 8192 + w * 1024]);
  };

  // Q fp8 fragments in registers: row qBase+q, K=512 as 16 chunks of 32.
  long qfr8[16];
  {
    const float* qsrc = query + (size_t)(qBase + q) * Dn;
#pragma unroll
    for (int ks = 0; ks < 16; ++ks) {
      f32x4 a = *(const f32x4*)&qsrc[ks * 32 + g * 8];
      f32x4 b = *(const f32x4*)&qsrc[ks * 32 + g * 8 + 4];
      union { u8 c[8]; long l; } u;
#pragma unroll
      for (int j = 0; j < 4; ++j) {
        u.c[j] = f8rn(a[j]);
        u.c[4 + j] = f8rn(b[j]);
      }
      qfr8[ks] = u.l;
    }
  }

  f32x16 O[8];
#pragma unroll
  for (int i = 0; i < 8; ++i) O[i] = (f32x16)(0.f);
  if (tid < 128) zacc[tid] = 0.f;

  stage_ms(0, cy * 4096, 0);
  stage_ms(1, cy * 4096, 1);

  for (int ct = 0; ct < 32; ++ct) {
    const int cBase = cy * 4096 + ct * 128;
    const int cNext = cy * 4096 + ((ct + 1) & 31) * 128;

    // ---- QK phases kk=0..3 (K-chunks of 128 fp8): consume Ms[kk%3] ----
    f32x4 S[8];
#pragma unroll
    for (int i = 0; i < 8; ++i) S[i] = (f32x4){0.f, 0.f, 0.f, 0.f};
#pragma unroll
    for (int kk = 0; kk < 4; ++kk) {
      WAITV2;
      WAITL0;
      BAR;
      if (kk < 2) stage_ms((kk + 2) % 3, cBase, kk + 2);
      else if (kk == 2) stage_mt(0, cBase, 0);
      else stage_mt(1, cBase, 1);
      __builtin_amdgcn_s_setprio(1);
#pragma unroll
      for (int ks = 0; ks < 4; ++ks) {
#pragma unroll
        for (int mi = 0; mi < 8; ++mi) {
          int row = mi * 16 + l15;
          long a = *(const long*)&L[LMS + (kk % 3) * 16384 + row * 128 +
                                    (((ks * 2 + (g >> 1)) ^ (row & 7)) << 4) +
                                    (g & 1) * 8];
          S[mi] = MFMA8(a, qfr8[kk * 4 + ks], S[mi]);
        }
      }
      __builtin_amdgcn_s_setprio(0);
    }

    // ---- P phase: exp(S*SC64) -> Ps (unnormalized); z partial. No stage. ----
    float zl = 0.f;
#pragma unroll
    for (int mi = 0; mi < 8; ++mi) {
      s16x4 p;
#pragma unroll
      for (int r = 0; r < 4; ++r) {
        float e = __expf(S[mi][r] * SC64);
        zl += e;
        p[r] = (short)bfrn(e);
      }
      int u16 = (mi * 2 + (g >> 1)) ^ l15;
      *(s16x4*)&L[LPS + q * 256 + u16 * 16 + (g & 1) * 8] = p;
    }
    zl += __shfl_xor(zl, 16);
    zl += __shfl_xor(zl, 32);
    if (g == 0) zred[q] = zl;
    WAITL0;
    BAR;
    if (tid < 128) zacc[tid] += zred[tid];

    // ---- PV phases u=0..7: 32x32x16 bf16; wave = (dt, qg x 2 q-tiles) ----
#pragma unroll
    for (int u = 0; u < 8; ++u) {
      WAITV2;
      WAITL0;
      BAR;
      if (u < 6) stage_mt((u + 2) % 3, cBase, u + 2);
      else if (u == 6) stage_ms(0, cNext, 0);
      else stage_ms(1, cNext, 1);
      __builtin_amdgcn_s_setprio(1);
#pragma unroll
      for (int kc = 0; kc < 4; ++kc) {
        int d = dt * 32 + l31;
        s16x8 am = *(const s16x8*)&L[LMT + (u % 3) * 16384 + d * 128 +
                                     (((kc * 2 + h) ^ (d & 7)) << 4)];
#pragma unroll
        for (int tqi = 0; tqi < 2; ++tqi) {
          int qq = qg * 64 + tqi * 32 + l31;
          s16x8 pb = *(const s16x8*)&L[LPS + qq * 256 +
                                       ((((u & 1) * 8 + kc * 2 + h) ^ (qq & 15)) << 4)];
          O[(u >> 1) * 2 + tqi] = MFMAB32(am, pb, O[(u >> 1) * 2 + tqi]);
        }
      }
      __builtin_amdgcn_s_setprio(0);
    }
  }

  // ---- epilogue: drain, z store, O via 4-pass [32q][512d] LDS transpose ----
  __syncthreads();
  if (tid < 128) zp2[(size_t)cy * ROWS + qBase + tid] = zacc[tid];
#pragma unroll
  for (int p = 0; p < 4; ++p) {
    __syncthreads();
    if (qg == (p >> 1)) {
      const int tqi = p & 1;
#pragma unroll
      for (int db = 0; db < 4; ++db)
#pragma unroll
        for (int r2 = 0; r2 < 4; ++r2) {
          s16x4 ov;
#pragma unroll
          for (int j = 0; j < 4; ++j) ov[j] = (short)bfrn(O[db * 2 + tqi][r2 * 4 + j]);
          int u8i = db * 32 + dt * 8 + r2 * 2 + h;  // d>>2 unit
          int u8s = u8i ^ ((l31 & 15) << 1);
          *(s16x4*)&L[LPS + l31 * 1024 + u8s * 8] = ov;
        }
    }
    __syncthreads();
#pragma unroll
    for (int i = 0; i < 4; ++i) {
      int slot = i * 512 + tid;
      int ql = slot >> 6, u16 = slot & 63;
      s16x8 v = *(const s16x8*)&L[LPS + ql * 1024 + ((u16 ^ (ql & 15)) << 4)];
      *(s16x8*)&opart[((size_t)cy * ROWS + qBase + p * 32 + ql) * Dn + u16 * 8] = v;
    }
  }
}

// out = (sum_cy opart[cy]) / (sum_cy zp2[cy]) per row
__global__ void k_merge(const ush* __restrict__ opart, const float* __restrict__ zp2,
                        float* __restrict__ out) {
  size_t i = ((size_t)blockIdx.x * 256 + threadIdx.x) * 4;
  int row = (int)(i >> 9);
  float z = 0.f;
#pragma unroll
  for (int cyy = 0; cyy < 8; ++cyy) z += zp2[(size_t)cyy * ROWS + row];
  float inv = 1.0f / z;
  f32x4 acc = {0.f, 0.f, 0.f, 0.f};
#pragma unroll
  for (int cyy = 0; cyy < 8; ++cyy) {
    s16x4 a = *(const s16x4*)&opart[(size_t)cyy * ROWS * Dn + i];
#pragma unroll
    for (int j = 0; j < 4; ++j) acc[j] += bff((ush)a[j]);
  }
#pragma unroll
  for (int j = 0; j < 4; ++j) acc[j] *= inv;
  *(f32x4*)&out[i] = acc;
}

extern "C" void kernel_launch(void* const* d_in, const int* in_sizes, int n_in,
                              void* d_out, int out_size, void* d_ws, size_t ws_size,
                              hipStream_t stream) {
  const float* keys = (const float*)d_in[0];
  const float* values = (const float*)d_in[1];
  const float* importance = (const float*)d_in[2];
  const float* query = (const float*)d_in[3];
  const float* mem = (const float*)d_in[4];
  char* wsb = (char*)d_ws;
  u8* nm8    = (u8*)(wsb + OFF_NM8);
  ush* nmT   = (ush*)(wsb + OFF_NMT);
  ush* mhf   = (ush*)(wsb + OFF_NMT);  // alias (dead after k_usage; nmT written later)
  ush* khf   = (ush*)(wsb + OFF_KHF);
  ush* opart = (ush*)(wsb + OFF_OPART);
  float* zpart = (float*)(wsb + OFF_ZPART);
  float* prio  = (float*)(wsb + OFF_PRIO);
  int* rank    = (int*)(wsb + OFF_RANK);
  float* comb  = (float*)(wsb + OFF_COMB);
  float* zp2   = (float*)(wsb + OFF_ZP2);
  float* invl1 = (float*)(wsb + OFF_COMB + 64);
  float* out = (float*)d_out;

  k_combined<<<Bn, 256, 0, stream>>>(importance, comb);
  k_cvt_all<<<18432, 256, 0, stream>>>(mem, keys, mhf, khf);
  k_rowexp<<<CAPn / 64, 256, 0, stream>>>(mhf, khf, zpart);
  k_invl<<<ROWS / 256, 256, 0, stream>>>(zpart, invl1);
  k_usage<<<dim3(CAPn / 128, Bn), 256, 0, stream>>>(mhf, khf, invl1, comb, prio);
  k_rankinit<<<(Bn * CAPn) / 256, 256, 0, stream>>>(rank);
  k_select<<<Bn, 1024, 0, stream>>>(prio, rank);
  k_newmem8<<<(CAPn * Dn / 4) / 256, 256, 0, stream>>>(mem, values, rank, nm8);
  k_nmT<<<dim3(CAPn / 64, Dn / 64), 256, 0, stream>>>(mem, values, rank, nmT);
  k_attnout<<<dim3(8, ROWS / 128), 512, 0, stream>>>(query, nm8, nmT, opart, zp2);
  k_merge<<<(ROWS * Dn / 4) / 256, 256, 0, stream>>>(opart, zp2, out);
}